// Round 1
// 439.126 us; speedup vs baseline: 1.1084x; 1.1084x over previous
//
#include <hip/hip_runtime.h>
#include <math.h>

#define TT 2048
#define DD 768
#define NN 256
#define NHH 12
#define BB 2
#define CH 512           // attention chunk (4 chunks of 4 x 128-tiles)

typedef unsigned short u16;
typedef __attribute__((ext_vector_type(8))) short bf16x8;
typedef __attribute__((ext_vector_type(8))) unsigned short u16x8;
typedef __attribute__((ext_vector_type(4))) float f32x4;

static inline int imin(int a, int b) { return a < b ? a : b; }

__device__ __forceinline__ u16 f2b(float f) {
  union { float f; unsigned u; } a; a.f = f;
  unsigned r = a.u + 0x7FFF + ((a.u >> 16) & 1);
  return (u16)(r >> 16);
}
__device__ __forceinline__ float b2f(u16 h) {
  union { unsigned u; float f; } a; a.u = ((unsigned)h) << 16;
  return a.f;
}

__device__ __forceinline__ void async16(const void* g, void* l) {
  __builtin_amdgcn_global_load_lds(
      (const __attribute__((address_space(1))) unsigned*)g,
      (__attribute__((address_space(3))) unsigned*)l, 16, 0, 0);
}

// Stage a 128x32 bf16 tile (row-major, ld in elements) into LDS [128][32].
__device__ __forceinline__ void stage128x32(
    const u16* __restrict__ gbase, size_t ld, u16* lds, int tid) {
  const int w = tid >> 6, l = tid & 63;
  const int r = l >> 2, kc = (l & 3) << 3;
#pragma unroll
  for (int q = 0; q < 2; ++q) {
    const int row0 = w * 32 + q * 16;
    async16(gbase + (size_t)(row0 + r) * ld + kc, lds + row0 * 32);
  }
}

// Stage a 64x32 bf16 tile into LDS [64][32]. One async16 per thread.
__device__ __forceinline__ void stage64x32(
    const u16* __restrict__ gbase, size_t ld, u16* lds, int tid) {
  const int w = tid >> 6, l = tid & 63;
  const int r = w * 16 + (l >> 2), kc = (l & 3) << 3;
  async16(gbase + (size_t)r * ld + kc, lds + w * 512);
}

// 16 MFMAs of one BK=32 step; wave (wr,wc) computes 64x64 of the 128x128 tile.
__device__ __forceinline__ void mfma_step(
    const u16* As, const u16* Bs, int wr, int wc, int lane, f32x4 acc[4][4]) {
  const int m16 = lane & 15, quad = lane >> 4;
  bf16x8 a[4], b[4];
#pragma unroll
  for (int i = 0; i < 4; ++i)
    a[i] = *(const bf16x8*)&As[(wr * 64 + i * 16 + m16) * 32 + quad * 8];
#pragma unroll
  for (int j = 0; j < 4; ++j)
    b[j] = *(const bf16x8*)&Bs[(wc * 64 + j * 16 + m16) * 32 + quad * 8];
#pragma unroll
  for (int i = 0; i < 4; ++i)
#pragma unroll
    for (int j = 0; j < 4; ++j)
      acc[i][j] = __builtin_amdgcn_mfma_f32_16x16x32_bf16(a[i], b[j], acc[i][j], 0, 0, 0);
}

// copy a 64x128 u16 tile from LDS (row-major, no pad) to global rows of ld.
__device__ __forceinline__ void copy_out64(
    const u16* buf, u16* g, size_t ld, int tid) {
#pragma unroll
  for (int s = 0; s < 4; ++s) {
    const int off = (s * 256 + tid) * 8;
    const int row = off >> 7, col = off & 127;
    *(u16x8*)&g[(size_t)row * ld + col] = *(const u16x8*)&buf[off];
  }
}

#define GEMM_PROLOGUE()                                            \
  __shared__ __attribute__((aligned(16))) u16 smem[16384];         \
  const int tid = threadIdx.x;                                     \
  const int w = tid >> 6, lane = tid & 63;                         \
  const int wr = w >> 1, wc = w & 1;                               \
  const int col16 = lane & 15, quad = lane >> 4;                   \
  f32x4 acc[4][4];                                                 \
  _Pragma("unroll") for (int i = 0; i < 4; ++i)                    \
  _Pragma("unroll") for (int j = 0; j < 4; ++j)                    \
      acc[i][j] = (f32x4){0.f, 0.f, 0.f, 0.f};

// Double-buffered, counted-vmcnt pipelined K loop (T3-lite 2-phase).
// Per step: 2x stage128x32 = 4 async16/thread -> vmcnt(4) keeps next panel
// in flight across the raw barrier; loads overlap current panel's MFMAs.
// Raw s_barrier (NOT __syncthreads: that drains vmcnt(0)). sched_barrier(0)
// pins ds_read/MFMA inside the phase (guide rule 18).
#define PIPELINED_K_LOOP(ABASE, ALD, BBASE, BLD, KTOT)                      \
  {                                                                         \
    u16* bA_ = smem; u16* bB_ = smem + 8192;                                \
    stage128x32((ABASE), (ALD), bA_, tid);                                  \
    stage128x32((BBASE), (BLD), bA_ + 4096, tid);                           \
    const int nk_ = (KTOT) / 32;                                            \
    for (int kp_ = 0; kp_ < nk_; ++kp_) {                                   \
      u16* cb_ = (kp_ & 1) ? bB_ : bA_;                                     \
      u16* nb_ = (kp_ & 1) ? bA_ : bB_;                                     \
      if (kp_ + 1 < nk_) {                                                  \
        const int kn_ = (kp_ + 1) * 32;                                     \
        stage128x32((ABASE) + kn_, (ALD), nb_, tid);                        \
        stage128x32((BBASE) + kn_, (BLD), nb_ + 4096, tid);                 \
        asm volatile("s_waitcnt vmcnt(4)" ::: "memory");                    \
      } else {                                                              \
        asm volatile("s_waitcnt vmcnt(0)" ::: "memory");                    \
      }                                                                     \
      __builtin_amdgcn_s_barrier();                                         \
      __builtin_amdgcn_sched_barrier(0);                                    \
      mfma_step(cb_, cb_ + 4096, wr, wc, lane, acc);                        \
      __builtin_amdgcn_sched_barrier(0);                                    \
      __builtin_amdgcn_s_barrier();                                         \
    }                                                                       \
  }

// ---------------------------------------------------------------------------
__global__ __launch_bounds__(256) void cvt_bf16(
    const float* __restrict__ in, u16* __restrict__ out, size_t n4) {
  size_t i = ((size_t)blockIdx.x * 256 + threadIdx.x) * 4;
  if (i >= n4 * 4) return;
  float4 v = *(const float4*)&in[i];
  u16 o[4] = {f2b(v.x), f2b(v.y), f2b(v.z), f2b(v.w)};
  *(ushort4*)&out[i] = *(ushort4*)o;
}

__global__ __launch_bounds__(256) void tcvt_bf16(
    const float* __restrict__ in, u16* __restrict__ out, int R, int C,
    size_t inStride, size_t outStride) {
  __shared__ float tile[32][33];
  const float* ip = in + (size_t)blockIdx.z * inStride;
  u16* op = out + (size_t)blockIdx.z * outStride;
  const int c0 = blockIdx.x * 32, r0 = blockIdx.y * 32;
  const int tx = threadIdx.x & 31, ty = threadIdx.x >> 5;
#pragma unroll
  for (int p = 0; p < 4; ++p)
    tile[ty + p * 8][tx] = ip[(size_t)(r0 + ty + p * 8) * C + c0 + tx];
  __syncthreads();
#pragma unroll
  for (int p = 0; p < 4; ++p)
    op[(size_t)(c0 + ty + p * 8) * R + r0 + tx] = f2b(tile[tx][ty + p * 8]);
}

__global__ __launch_bounds__(256) void k_colsum(
    const u16* __restrict__ encvt, float* __restrict__ colsum) {
  const int row = blockIdx.x * 4 + (threadIdx.x >> 6);
  const int lane = threadIdx.x & 63;
  const u16* pr = encvt + (size_t)row * DD;
  float s = 0.f;
#pragma unroll
  for (int i = 0; i < 3; ++i) {
    ushort4 v = *(const ushort4*)&pr[(lane << 2) + i * 256];
    s += b2f(v.x) + b2f(v.y) + b2f(v.z) + b2f(v.w);
  }
#pragma unroll
  for (int off = 32; off; off >>= 1) s += __shfl_xor(s, off);
  if (lane == 0) colsum[row] = s;
}

// ---------------------------------------------------------------------------
// K1: latent = X16 @ ENCT[h]^T; relu; rope -> QR16 [b][h][t][n] AND
// QRT16 [b][h][n][t].  M=4096, N=256, K=768 per head.
// ---------------------------------------------------------------------------
__global__ __launch_bounds__(256) void k1_encode(
    const u16* __restrict__ x16, const u16* __restrict__ enct,
    u16* __restrict__ qr16, u16* __restrict__ qrt16) {
  const int h = blockIdx.z;
  const int m0 = blockIdx.x * 128, n0 = blockIdx.y * 128;
  GEMM_PROLOGUE();
  PIPELINED_K_LOOP(x16 + (size_t)m0 * DD, DD,
                   enct + ((size_t)h * NN + n0) * DD, DD, DD);
#pragma unroll
  for (int p = 0; p < 2; ++p) {
    __syncthreads();
    if (wr == p) {
#pragma unroll
      for (int i = 0; i < 4; ++i)
#pragma unroll
        for (int j = 0; j < 4; ++j) {
          const int n = n0 + wc * 64 + j * 16 + col16;
          const int q = n & ~1;
          const float freq = exp2f((float)q * -0.0625f) * 0.15915494309189535f;
          float rv[4], pv[4];
#pragma unroll
          for (int r = 0; r < 4; ++r) rv[r] = fmaxf(acc[i][j][r], 0.f);
#pragma unroll
          for (int r = 0; r < 4; ++r) pv[r] = __shfl_xor(rv[r], 1);
#pragma unroll
          for (int r = 0; r < 4; ++r) {
            const int lr = i * 16 + quad * 4 + r;
            const int t = (m0 + p * 64 + lr) & (TT - 1);
            float phase = (float)t * freq;
            float ph = (phase - floorf(phase)) * 6.283185307179586f;
            float s = __sinf(ph), c = __cosf(ph);
            float o = (n & 1) ? (rv[r] * c + pv[r] * s) : (rv[r] * c - pv[r] * s);
            smem[lr * 128 + wc * 64 + j * 16 + col16] = f2b(o);
          }
        }
    }
    __syncthreads();
    const int m = m0 + p * 64;
    const int b = m >> 11, tb = m & (TT - 1);
    const size_t sl = (size_t)(b * NHH + h);
    copy_out64(smem, qr16 + (sl * TT + tb) * NN + n0, NN, tid);
    // transposed copy: QRT16[sl][n][t] = tile[t][n]
#pragma unroll
    for (int s = 0; s < 4; ++s) {
      const int off = (s * 256 + tid) * 8;
      const int nr = off >> 6, tc = off & 63;
      u16 vals[8];
#pragma unroll
      for (int k = 0; k < 8; ++k) vals[k] = smem[(tc + k) * 128 + nr];
      *(u16x8*)&qrt16[(sl * NN + n0 + nr) * TT + tb + tc] = *(u16x8*)vals;
    }
  }
}

// ---------------------------------------------------------------------------
// kS: block-diagonal band of S = QR QR^T (strict lower), 40 tiles/slice.
// SB (group-local) [gs][TT][CH], sc = s - 512*(t/512).
// ---------------------------------------------------------------------------
__global__ __launch_bounds__(256) void kS_band(
    const u16* __restrict__ qr16, u16* __restrict__ sb, int bh0) {
  const int z = blockIdx.y;                  // group-local slice
  const int bh = bh0 + z;
  const int cc = blockIdx.x / 10, rr = blockIdx.x % 10;
  int i = (int)((sqrtf(8.f * rr + 1.f) - 1.f) * 0.5f);
  while ((i + 1) * (i + 2) / 2 <= rr) ++i;
  while (i * (i + 1) / 2 > rr) --i;
  const int j = rr - i * (i + 1) / 2;
  const int t0 = (cc * 4 + i) * 128;
  const int s0 = cc * CH + j * 128;
  const u16* q = qr16 + (size_t)bh * TT * NN;
  GEMM_PROLOGUE();
  PIPELINED_K_LOOP(q + (size_t)t0 * NN, NN, q + (size_t)s0 * NN, NN, NN);
  const bool diag = (i == j);
#pragma unroll
  for (int p = 0; p < 2; ++p) {
    __syncthreads();
    if (wr == p) {
#pragma unroll
      for (int ii = 0; ii < 4; ++ii)
#pragma unroll
        for (int jj = 0; jj < 4; ++jj) {
          const int s = s0 + wc * 64 + jj * 16 + col16;
#pragma unroll
          for (int r = 0; r < 4; ++r) {
            const int lr = ii * 16 + quad * 4 + r;
            const int t = t0 + p * 64 + lr;
            float v = acc[ii][jj][r];
            if (diag && s >= t) v = 0.f;
            smem[lr * 128 + wc * 64 + jj * 16 + col16] = f2b(v);
          }
        }
    }
    __syncthreads();
    copy_out64(smem, sb + ((size_t)z * TT + t0 + p * 64) * CH + j * 128, CH, tid);
  }
}

// ---------------------------------------------------------------------------
// kB_all: ONE launch. Each block owns a 64(d) x 128(n) tile of H and runs
// K = 0..1536 with fp32 accumulators, writing bf16 snapshot H16[z][c] at each
// chunk boundary (c = 0,1,2). Grid (12, 2, gs).
// ---------------------------------------------------------------------------
__global__ __launch_bounds__(256) void kB_all(
    const u16* __restrict__ xt16, const u16* __restrict__ qrt16,
    u16* __restrict__ h16, int bh0) {
  __shared__ __attribute__((aligned(16))) u16 sm[8192];
  u16* As = sm;          // 64 x 32
  u16* Bs = sm + 2048;   // 128 x 32
  const int tid = threadIdx.x;
  const int w = tid >> 6, lane = tid & 63;
  const int m16 = lane & 15, quad = lane >> 4;
  const int z = blockIdx.z;
  const int bh = bh0 + z, b = bh / NHH;
  const int d0 = blockIdx.x * 64, n0 = blockIdx.y * 128;
  f32x4 acc[4][2];
#pragma unroll
  for (int i = 0; i < 4; ++i)
#pragma unroll
    for (int j = 0; j < 2; ++j) acc[i][j] = (f32x4){0.f, 0.f, 0.f, 0.f};
  const u16* Ab = xt16 + ((size_t)b * DD + d0) * TT;
  const u16* Bb = qrt16 + ((size_t)bh * NN + n0) * TT;
  for (int c = 0; c < 3; ++c) {
    for (int k0 = c * CH; k0 < (c + 1) * CH; k0 += 32) {
      stage64x32(Ab + k0, TT, As, tid);
      stage128x32(Bb + k0, TT, Bs, tid);
      __syncthreads();
      bf16x8 a[4], bb[2];
#pragma unroll
      for (int i = 0; i < 4; ++i)
        a[i] = *(const bf16x8*)&As[(i * 16 + m16) * 32 + quad * 8];
#pragma unroll
      for (int j = 0; j < 2; ++j)
        bb[j] = *(const bf16x8*)&Bs[(w * 32 + j * 16 + m16) * 32 + quad * 8];
#pragma unroll
      for (int i = 0; i < 4; ++i)
#pragma unroll
        for (int j = 0; j < 2; ++j)
          acc[i][j] = __builtin_amdgcn_mfma_f32_16x16x32_bf16(a[i], bb[j], acc[i][j], 0, 0, 0);
      __syncthreads();
    }
    // snapshot H16[z][c]: restage 64x128 fp32->bf16 via LDS, coalesced store
#pragma unroll
    for (int i = 0; i < 4; ++i)
#pragma unroll
      for (int j = 0; j < 2; ++j)
#pragma unroll
        for (int r = 0; r < 4; ++r)
          sm[(i * 16 + quad * 4 + r) * 128 + w * 32 + j * 16 + m16] =
              f2b(acc[i][j][r]);
    __syncthreads();
    u16* hd = h16 + (size_t)(z * 3 + c) * DD * NN;
#pragma unroll
    for (int s = 0; s < 4; ++s) {
      const int off = (s * 256 + tid) * 8;
      const int row = off >> 7, col = off & 127;
      *(u16x8*)&hd[(size_t)(d0 + row) * NN + n0 + col] = *(const u16x8*)&sm[off];
    }
    __syncthreads();
  }
}

// ---------------------------------------------------------------------------
// kA: 128x128 output, unified panel-pipelined K sequence:
//   panels 0..3 (if c>0): QR[t-tile] @ H16[z][c-1]^T  (K=256)
//   panels after: for j<=it, SB tile @ XT16 (K=128 each, 2 panels/j)
// Double-buffered LDS (64KB), counted vmcnt(8), raw barriers.
// LPT: tt order descending by work so stragglers launch first.
// Grid (6, 16, gs).
// ---------------------------------------------------------------------------
__device__ static const int TTORD[16] = {15, 11, 7, 14, 10, 6, 13, 9,
                                         5, 3, 12, 8, 4, 2, 1, 0};

__global__ __launch_bounds__(256) void kA_attn(
    const u16* __restrict__ qr16, const u16* __restrict__ h16,
    const u16* __restrict__ sb, const u16* __restrict__ xt16,
    u16* __restrict__ ykv16, int bh0) {
  __shared__ __attribute__((aligned(16))) u16 smem[32768];  // 2 x 32KB buffers
  const int tid = threadIdx.x;
  const int w = tid >> 6, lane = tid & 63;
  const int wr = w >> 1, wc = w & 1;
  const int col16 = lane & 15, quad = lane >> 4;
  const int z = blockIdx.z;
  const int bh = bh0 + z, b = bh / NHH;
  const int tt = TTORD[blockIdx.y];          // LPT-ordered t-tile 0..15
  const int c = tt >> 2, it = tt & 3;
  const int d0 = blockIdx.x * 128;
  const int t0 = tt * 128;
  f32x4 acc[4][4];
#pragma unroll
  for (int i = 0; i < 4; ++i)
#pragma unroll
    for (int j = 0; j < 4; ++j) acc[i][j] = (f32x4){0.f, 0.f, 0.f, 0.f};

  const int c4 = (c > 0) ? 4 : 0;
  const int nP = c4 + (it + 1) * 2;          // BK=64 panels total
  const u16* hs = h16 + ((size_t)(z * 3 + (c > 0 ? c - 1 : 0)) * DD + d0) * NN;
  const u16* qb = qr16 + ((size_t)bh * TT + t0) * NN;
  const u16* sbb = sb + ((size_t)z * TT + t0) * CH;
  const u16* xb = xt16 + ((size_t)b * DD + d0) * TT + c * CH;

  // Stage panel p (A: 128x64 as two 128x32, B likewise) into buf[0..16383].
#define KA_STAGE(buf, p)                                                  \
  {                                                                       \
    const u16 *pa_, *pb_; size_t la_, lb_;                                \
    if ((p) < c4) {                                                       \
      pa_ = qb + (p) * 64; la_ = NN;                                      \
      pb_ = hs + (p) * 64; lb_ = NN;                                      \
    } else {                                                              \
      const int q_ = (p) - c4;                                            \
      const int j_ = q_ >> 1, kk_ = (q_ & 1) << 6;                        \
      pa_ = sbb + j_ * 128 + kk_; la_ = CH;                               \
      pb_ = xb + j_ * 128 + kk_; lb_ = TT;                                \
    }                                                                     \
    stage128x32(pa_, la_, (buf), tid);                                    \
    stage128x32(pa_ + 32, la_, (buf) + 4096, tid);                        \
    stage128x32(pb_, lb_, (buf) + 8192, tid);                             \
    stage128x32(pb_ + 32, lb_, (buf) + 12288, tid);                       \
  }

  u16* bufA = smem;
  u16* bufB = smem + 16384;
  KA_STAGE(bufA, 0);
  for (int p = 0; p < nP; ++p) {
    u16* cb = (p & 1) ? bufB : bufA;
    u16* nb = (p & 1) ? bufA : bufB;
    if (p + 1 < nP) {
      KA_STAGE(nb, p + 1);
      // 8 async16/thread just issued for p+1: allow them to stay in flight,
      // wait only for panel p's 8 (the oldest) to have landed.
      asm volatile("s_waitcnt vmcnt(8)" ::: "memory");
    } else {
      asm volatile("s_waitcnt vmcnt(0)" ::: "memory");
    }
    __builtin_amdgcn_s_barrier();            // publish panel p across waves
    __builtin_amdgcn_sched_barrier(0);       // pin reads/MFMAs after barrier
    mfma_step(cb, cb + 8192, wr, wc, lane, acc);
    mfma_step(cb + 4096, cb + 12288, wr, wc, lane, acc);
    __builtin_amdgcn_sched_barrier(0);       // pin reads/MFMAs before barrier
    __builtin_amdgcn_s_barrier();            // reads of cb done before overwrite
  }
#undef KA_STAGE

#pragma unroll
  for (int p = 0; p < 2; ++p) {
    __syncthreads();
    if (wr == p) {
#pragma unroll
      for (int i = 0; i < 4; ++i)
#pragma unroll
        for (int j = 0; j < 4; ++j)
#pragma unroll
          for (int r = 0; r < 4; ++r) {
            const int lr = i * 16 + quad * 4 + r;
            smem[lr * 128 + wc * 64 + j * 16 + col16] = f2b(acc[i][j][r]);
          }
    }
    __syncthreads();
    copy_out64(smem, ykv16 + ((size_t)z * TT + t0 + p * 64) * DD + d0, DD, tid);
  }
}

// ---------------------------------------------------------------------------
// K3: per-row mean/rstd of group-local ykv16 (bf16 rows of 768). 1 wave/row.
// ---------------------------------------------------------------------------
__global__ __launch_bounds__(256) void k3_stats(
    const u16* __restrict__ ykv16, float* __restrict__ mu, float* __restrict__ rs) {
  const int row = blockIdx.x * 4 + (threadIdx.x >> 6);
  const int lane = threadIdx.x & 63;
  const u16* p = ykv16 + (size_t)row * DD;
  float sum = 0.f, sq = 0.f;
#pragma unroll
  for (int i = 0; i < 3; ++i) {
    ushort4 v = *(const ushort4*)&p[(lane << 2) + i * 256];
    float f0 = b2f(v.x), f1 = b2f(v.y), f2 = b2f(v.z), f3 = b2f(v.w);
    sum += f0 + f1 + f2 + f3;
    sq += f0 * f0 + f1 * f1 + f2 * f2 + f3 * f3;
  }
#pragma unroll
  for (int off = 32; off; off >>= 1) {
    sum += __shfl_xor(sum, off);
    sq += __shfl_xor(sq, off);
  }
  if (lane == 0) {
    float m = sum * (1.f / 768.f);
    float v = sq * (1.f / 768.f) - m * m;
    mu[row] = m;
    rs[row] = rsqrtf(v + 1e-5f);
  }
}

// ---------------------------------------------------------------------------
// K4: raw GEMM ykv16 @ ENCVT[h]^T with LN as epilogue affine; xs via inverse
// rope of QR16; out2 = xs*ys (fp32); XY (bf16) written IN PLACE into QR16's
// storage (reads of QR complete behind a barrier before the writes).
// ---------------------------------------------------------------------------
__global__ __launch_bounds__(256) void k4_xy(
    const u16* __restrict__ ykv16, const u16* __restrict__ encvt,
    u16* __restrict__ qrxy, const float* __restrict__ mu,
    const float* __restrict__ rs, const float* __restrict__ colsum,
    float* __restrict__ out2, int bh0) {
  const int z = blockIdx.z;
  const int bh = bh0 + z, h = bh % NHH;
  const int t0 = blockIdx.x * 128, n0 = blockIdx.y * 128;
  GEMM_PROLOGUE();
  PIPELINED_K_LOOP(ykv16 + ((size_t)z * TT + t0) * DD, DD,
                   encvt + ((size_t)h * NN + n0) * DD, DD, DD);
#pragma unroll
  for (int p = 0; p < 2; ++p) {
    __syncthreads();
    if (wr == p) {
#pragma unroll
      for (int i = 0; i < 4; ++i)
#pragma unroll
        for (int j = 0; j < 4; ++j) {
          const int n = n0 + wc * 64 + j * 16 + col16;
          const int qn = n & ~1;
          const float freq = exp2f((float)qn * -0.0625f) * 0.15915494309189535f;
          const float cs = colsum[h * NN + n];
#pragma unroll
          for (int r = 0; r < 4; ++r) {
            const int lr = i * 16 + quad * 4 + r;
            const int t = t0 + p * 64 + lr;
            const int lrow = z * TT + t;
            const float muv = mu[lrow], rsv = rs[lrow];
            float ys = fmaxf(rsv * acc[i][j][r] - rsv * muv * cs, 0.f);
            const size_t gi = ((size_t)bh * TT + t) * NN + n;
            float qs = b2f(qrxy[gi]);
            float qp = b2f(qrxy[gi ^ 1]);
            float phase = (float)t * freq;
            float ph = (phase - floorf(phase)) * 6.283185307179586f;
            float s = __sinf(ph), c2 = __cosf(ph);
            float xs = (n & 1) ? (qs * c2 - qp * s) : (qs * c2 + qp * s);
            float val = ys * xs;
            out2[gi] = val;
            smem[lr * 128 + wc * 64 + j * 16 + col16] = f2b(val);
          }
        }
    }
    __syncthreads();
    copy_out64(smem, qrxy + ((size_t)bh * TT + t0 + p * 64) * NN + n0, NN, tid);
  }
}

// ---------------------------------------------------------------------------
// K5: ymlp = flat(XY) @ DECT^T.  M=4096, N=768, K=3072.  64x64 tiles
// (768 blocks); A gathered from XY's [b][h][t][n] layout (in QR16 storage).
// ---------------------------------------------------------------------------
__global__ __launch_bounds__(256) void k5_mlp(
    const u16* __restrict__ xyq, const u16* __restrict__ dect,
    float* __restrict__ ymlp) {
  __shared__ __attribute__((aligned(16))) u16 sm[4096];
  u16* As = sm;
  u16* Bs = sm + 2048;
  const int tid = threadIdx.x;
  const int w = tid >> 6, lane = tid & 63;
  const int wr = w >> 1, wc = w & 1;
  const int m16 = lane & 15, quad = lane >> 4;
  const int m0 = blockIdx.x * 64, d0 = blockIdx.y * 64;
  f32x4 acc[2][2];
#pragma unroll
  for (int i = 0; i < 2; ++i)
#pragma unroll
    for (int j = 0; j < 2; ++j) acc[i][j] = (f32x4){0.f, 0.f, 0.f, 0.f};
  const int ar = w * 16 + (lane >> 2);      // A row within 64-tile
  const int m = m0 + ar;
  const int b = m >> 11, t = m & (TT - 1);
  const int kc = (lane & 3) << 3;
  for (int k0 = 0; k0 < NHH * NN; k0 += 32) {
    const int hh = k0 >> 8;
    const int kk = (k0 & 255) + kc;
    async16(xyq + ((size_t)(b * NHH + hh) * TT + t) * NN + kk, As + w * 512);
    stage64x32(dect + (size_t)d0 * (NHH * NN) + k0, NHH * NN, Bs, tid);
    __syncthreads();
    bf16x8 a[2], bb[2];
#pragma unroll
    for (int i = 0; i < 2; ++i)
      a[i] = *(const bf16x8*)&As[(wr * 32 + i * 16 + m16) * 32 + quad * 8];
#pragma unroll
    for (int j = 0; j < 2; ++j)
      bb[j] = *(const bf16x8*)&Bs[(wc * 32 + j * 16 + m16) * 32 + quad * 8];
#pragma unroll
    for (int i = 0; i < 2; ++i)
#pragma unroll
      for (int j = 0; j < 2; ++j)
        acc[i][j] = __builtin_amdgcn_mfma_f32_16x16x32_bf16(a[i], bb[j], acc[i][j], 0, 0, 0);
    __syncthreads();
  }
#pragma unroll
  for (int i = 0; i < 2; ++i)
#pragma unroll
    for (int j = 0; j < 2; ++j) {
      const int d = d0 + wc * 32 + j * 16 + m16;
#pragma unroll
      for (int r = 0; r < 4; ++r) {
        const int mm = m0 + wr * 32 + i * 16 + quad * 4 + r;
        ymlp[(size_t)mm * DD + d] = acc[i][j][r];
      }
    }
}

// ---------------------------------------------------------------------------
// K6: y = ln(ymlp)*sqrt(0.1/(ra+1e-6))*scale; out1 = ln(x+y). Block per row.
// ymlp aliases out1 (in-place per row).
// ---------------------------------------------------------------------------
__global__ __launch_bounds__(256) void k6_final(
    const float* __restrict__ ymlp, const float* __restrict__ x,
    const float* __restrict__ scale, const float* __restrict__ ra,
    float* __restrict__ out1) {
  const int row = blockIdx.x;
  const int tid = threadIdx.x;
  const int wid = tid >> 6, lane = tid & 63;
  __shared__ float red[8];
  float v[3];
  float sum = 0.f, sq = 0.f;
#pragma unroll
  for (int j = 0; j < 3; ++j) {
    v[j] = ymlp[(size_t)row * DD + tid + j * 256];
    sum += v[j]; sq += v[j] * v[j];
  }
#pragma unroll
  for (int off = 32; off; off >>= 1) { sum += __shfl_xor(sum, off); sq += __shfl_xor(sq, off); }
  if (lane == 0) { red[wid] = sum; red[4 + wid] = sq; }
  __syncthreads();
  sum = red[0] + red[1] + red[2] + red[3];
  sq = red[4] + red[5] + red[6] + red[7];
  const float m1 = sum * (1.f / 768.f);
  const float r1 = rsqrtf(sq * (1.f / 768.f) - m1 * m1 + 1e-5f);
  float z[3];
  float sum2 = 0.f, sq2 = 0.f;
#pragma unroll
  for (int j = 0; j < 3; ++j) {
    const int d = tid + j * 256;
    float y = (v[j] - m1) * r1 * sqrtf(0.1f / (ra[d] + 1e-6f)) * scale[d];
    z[j] = x[(size_t)row * DD + d] + y;
    sum2 += z[j]; sq2 += z[j] * z[j];
  }
  __syncthreads();
#pragma unroll
  for (int off = 32; off; off >>= 1) { sum2 += __shfl_xor(sum2, off); sq2 += __shfl_xor(sq2, off); }
  if (lane == 0) { red[wid] = sum2; red[4 + wid] = sq2; }
  __syncthreads();
  sum2 = red[0] + red[1] + red[2] + red[3];
  sq2 = red[4] + red[5] + red[6] + red[7];
  const float m2 = sum2 * (1.f / 768.f);
  const float r2 = rsqrtf(sq2 * (1.f / 768.f) - m2 * m2 + 1e-5f);
#pragma unroll
  for (int j = 0; j < 3; ++j)
    out1[(size_t)row * DD + tid + j * 256] = (z[j] - m2) * r2;
}

// ---------------------------------------------------------------------------
extern "C" void kernel_launch(void* const* d_in, const int* in_sizes, int n_in,
                              void* d_out, int out_size, void* d_ws, size_t ws_size,
                              hipStream_t stream) {
  const float* x = (const float*)d_in[0];
  const float* enc = (const float*)d_in[1];
  const float* encv = (const float*)d_in[2];
  const float* dec = (const float*)d_in[3];
  const float* scale = (const float*)d_in[4];
  const float* ra = (const float*)d_in[5];
  float* out1 = (float*)d_out;
  float* out2 = out1 + (size_t)BB * TT * DD;
  float* ymlp = out1;                         // k5 scratch, k6 in-place

  const int NS = BB * NHH;  // 24 slices
  unsigned char* p = (unsigned char*)d_ws;
  u16* X16 = (u16*)p;    p += (size_t)BB * TT * DD * 2;
  u16* XT16 = (u16*)p;   p += (size_t)BB * DD * TT * 2;
  u16* ENCT = (u16*)p;   p += (size_t)NHH * NN * DD * 2;
  u16* ENCVT = (u16*)p;  p += (size_t)NHH * NN * DD * 2;
  u16* DECT = (u16*)p;   p += (size_t)DD * NHH * NN * 2;
  u16* QR16 = (u16*)p;   p += (size_t)NS * TT * NN * 2;   // holds QR, then XY
  u16* QRT16 = (u16*)p;  p += (size_t)NS * NN * TT * 2;
  float* COLSUM = (float*)p; p += (size_t)NHH * NN * 4;
  // Adaptive, BALANCED per-slice attention pool:
  //   SB (TT*CH bf16) + H16 (3 snapshots DD*NN bf16) + YKV16 (TT*DD bf16)
  //   + MU/RS (TT f32 each)
  const size_t SLICE_B = (size_t)TT * CH * 2 + 3 * (size_t)DD * NN * 2 +
                         (size_t)TT * DD * 2 + (size_t)TT * 8;
  size_t fixed = (size_t)(p - (unsigned char*)d_ws);
  size_t rem = (ws_size > fixed) ? ws_size - fixed : 0;
  int GSmax = (int)(rem / SLICE_B);
  if (GSmax < 1) GSmax = 1;
  if (GSmax > NS) GSmax = NS;
  const int ngrp = (NS + GSmax - 1) / GSmax;
  const int GS = (NS + ngrp - 1) / ngrp;     // balanced groups
  u16* SB = (u16*)p;     p += (size_t)GS * TT * CH * 2;
  u16* H16 = (u16*)p;    p += (size_t)GS * 3 * DD * NN * 2;
  u16* YKV16 = (u16*)p;  p += (size_t)GS * TT * DD * 2;
  float* MU = (float*)p; p += (size_t)GS * TT * 4;
  float* RS = (float*)p; p += (size_t)GS * TT * 4;

  // One-time conversions / transposes
  cvt_bf16<<<dim3((BB * TT * DD) / 1024), 256, 0, stream>>>(x, X16, (size_t)BB * TT * DD / 4);
  tcvt_bf16<<<dim3(DD / 32, TT / 32, BB), 256, 0, stream>>>(
      x, XT16, TT, DD, (size_t)TT * DD, (size_t)DD * TT);
  tcvt_bf16<<<dim3(NN / 32, DD / 32, NHH), 256, 0, stream>>>(
      enc, ENCT, DD, NN, (size_t)DD * NN, (size_t)NN * DD);
  tcvt_bf16<<<dim3(NN / 32, DD / 32, NHH), 256, 0, stream>>>(
      encv, ENCVT, DD, NN, (size_t)DD * NN, (size_t)NN * DD);
  tcvt_bf16<<<dim3(DD / 32, (NHH * NN) / 32, 1), 256, 0, stream>>>(
      dec, DECT, NHH * NN, DD, 0, 0);
  k_colsum<<<dim3(NHH * NN / 4), 256, 0, stream>>>(ENCVT, COLSUM);

  k1_encode<<<dim3(BB * TT / 128, NN / 128, NHH), 256, 0, stream>>>(
      X16, ENCT, QR16, QRT16);

  for (int bh0 = 0; bh0 < NS; bh0 += GS) {
    const int gs = imin(GS, NS - bh0);
    kS_band<<<dim3(40, gs), 256, 0, stream>>>(QR16, SB, bh0);
    kB_all<<<dim3(DD / 64, NN / 128, gs), 256, 0, stream>>>(
        XT16, QRT16, H16, bh0);
    kA_attn<<<dim3(DD / 128, TT / 128, gs), 256, 0, stream>>>(
        QR16, H16, SB, XT16, YKV16, bh0);
    k3_stats<<<dim3(gs * TT / 4), 256, 0, stream>>>(YKV16, MU, RS);
    k4_xy<<<dim3(TT / 128, NN / 128, gs), 256, 0, stream>>>(
        YKV16, ENCVT, QR16, MU, RS, COLSUM, out2, bh0);
  }

  k5_mlp<<<dim3(BB * TT / 64, DD / 64), 256, 0, stream>>>(QR16, DECT, ymlp);
  k6_final<<<dim3(BB * TT), 256, 0, stream>>>(ymlp, x, scale, ra, out1);
}

// Round 2
// 409.706 us; speedup vs baseline: 1.1880x; 1.0718x over previous
//
#include <hip/hip_runtime.h>
#include <math.h>

#define TT 2048
#define DD 768
#define NN 256
#define NHH 12
#define BB 2
#define CH 512           // attention chunk (4 chunks of 4 x 128-tiles)

typedef unsigned short u16;
typedef __attribute__((ext_vector_type(8))) short bf16x8;
typedef __attribute__((ext_vector_type(8))) unsigned short u16x8;
typedef __attribute__((ext_vector_type(4))) float f32x4;

static inline int imin(int a, int b) { return a < b ? a : b; }

__device__ __forceinline__ u16 f2b(float f) {
  union { float f; unsigned u; } a; a.f = f;
  unsigned r = a.u + 0x7FFF + ((a.u >> 16) & 1);
  return (u16)(r >> 16);
}
__device__ __forceinline__ float b2f(u16 h) {
  union { unsigned u; float f; } a; a.u = ((unsigned)h) << 16;
  return a.f;
}

__device__ __forceinline__ void async16(const void* g, void* l) {
  __builtin_amdgcn_global_load_lds(
      (const __attribute__((address_space(1))) unsigned*)g,
      (__attribute__((address_space(3))) unsigned*)l, 16, 0, 0);
}

// Stage a 128x32 bf16 tile (row-major, ld in elements) into LDS [128][32].
__device__ __forceinline__ void stage128x32(
    const u16* __restrict__ gbase, size_t ld, u16* lds, int tid) {
  const int w = tid >> 6, l = tid & 63;
  const int r = l >> 2, kc = (l & 3) << 3;
#pragma unroll
  for (int q = 0; q < 2; ++q) {
    const int row0 = w * 32 + q * 16;
    async16(gbase + (size_t)(row0 + r) * ld + kc, lds + row0 * 32);
  }
}

// Stage a 64x32 bf16 tile into LDS [64][32]. One async16 per thread.
__device__ __forceinline__ void stage64x32(
    const u16* __restrict__ gbase, size_t ld, u16* lds, int tid) {
  const int w = tid >> 6, l = tid & 63;
  const int r = w * 16 + (l >> 2), kc = (l & 3) << 3;
  async16(gbase + (size_t)r * ld + kc, lds + w * 512);
}

// 16 MFMAs of one BK=32 step; wave (wr,wc) computes 64x64 of the 128x128 tile.
__device__ __forceinline__ void mfma_step(
    const u16* As, const u16* Bs, int wr, int wc, int lane, f32x4 acc[4][4]) {
  const int m16 = lane & 15, quad = lane >> 4;
  bf16x8 a[4], b[4];
#pragma unroll
  for (int i = 0; i < 4; ++i)
    a[i] = *(const bf16x8*)&As[(wr * 64 + i * 16 + m16) * 32 + quad * 8];
#pragma unroll
  for (int j = 0; j < 4; ++j)
    b[j] = *(const bf16x8*)&Bs[(wc * 64 + j * 16 + m16) * 32 + quad * 8];
#pragma unroll
  for (int i = 0; i < 4; ++i)
#pragma unroll
    for (int j = 0; j < 4; ++j)
      acc[i][j] = __builtin_amdgcn_mfma_f32_16x16x32_bf16(a[i], b[j], acc[i][j], 0, 0, 0);
}

// copy a 64x128 u16 tile from LDS (row-major, no pad) to global rows of ld.
__device__ __forceinline__ void copy_out64(
    const u16* buf, u16* g, size_t ld, int tid) {
#pragma unroll
  for (int s = 0; s < 4; ++s) {
    const int off = (s * 256 + tid) * 8;
    const int row = off >> 7, col = off & 127;
    *(u16x8*)&g[(size_t)row * ld + col] = *(const u16x8*)&buf[off];
  }
}

#define GEMM_PROLOGUE()                                            \
  __shared__ __attribute__((aligned(16))) u16 smem[16384];         \
  const int tid = threadIdx.x;                                     \
  const int w = tid >> 6, lane = tid & 63;                         \
  const int wr = w >> 1, wc = w & 1;                               \
  const int col16 = lane & 15, quad = lane >> 4;                   \
  f32x4 acc[4][4];                                                 \
  _Pragma("unroll") for (int i = 0; i < 4; ++i)                    \
  _Pragma("unroll") for (int j = 0; j < 4; ++j)                    \
      acc[i][j] = (f32x4){0.f, 0.f, 0.f, 0.f};

// Double-buffered, counted-vmcnt pipelined K loop (T3-lite 2-phase).
// Per step: 2x stage128x32 = 4 async16/thread -> vmcnt(4) keeps next panel
// in flight across the raw barrier; loads overlap current panel's MFMAs.
// Raw s_barrier (NOT __syncthreads: that drains vmcnt(0)). sched_barrier(0)
// pins ds_read/MFMA inside the phase (guide rule 18).
#define PIPELINED_K_LOOP(ABASE, ALD, BBASE, BLD, KTOT)                      \
  {                                                                         \
    u16* bA_ = smem; u16* bB_ = smem + 8192;                                \
    stage128x32((ABASE), (ALD), bA_, tid);                                  \
    stage128x32((BBASE), (BLD), bA_ + 4096, tid);                           \
    const int nk_ = (KTOT) / 32;                                            \
    for (int kp_ = 0; kp_ < nk_; ++kp_) {                                   \
      u16* cb_ = (kp_ & 1) ? bB_ : bA_;                                     \
      u16* nb_ = (kp_ & 1) ? bA_ : bB_;                                     \
      if (kp_ + 1 < nk_) {                                                  \
        const int kn_ = (kp_ + 1) * 32;                                     \
        stage128x32((ABASE) + kn_, (ALD), nb_, tid);                        \
        stage128x32((BBASE) + kn_, (BLD), nb_ + 4096, tid);                 \
        asm volatile("s_waitcnt vmcnt(4)" ::: "memory");                    \
      } else {                                                              \
        asm volatile("s_waitcnt vmcnt(0)" ::: "memory");                    \
      }                                                                     \
      __builtin_amdgcn_s_barrier();                                         \
      __builtin_amdgcn_sched_barrier(0);                                    \
      mfma_step(cb_, cb_ + 4096, wr, wc, lane, acc);                        \
      __builtin_amdgcn_sched_barrier(0);                                    \
      __builtin_amdgcn_s_barrier();                                         \
    }                                                                       \
  }

// ---------------------------------------------------------------------------
__global__ __launch_bounds__(256) void cvt_bf16(
    const float* __restrict__ in, u16* __restrict__ out, size_t n4) {
  size_t i = ((size_t)blockIdx.x * 256 + threadIdx.x) * 4;
  if (i >= n4 * 4) return;
  float4 v = *(const float4*)&in[i];
  u16 o[4] = {f2b(v.x), f2b(v.y), f2b(v.z), f2b(v.w)};
  *(ushort4*)&out[i] = *(ushort4*)o;
}

__global__ __launch_bounds__(256) void tcvt_bf16(
    const float* __restrict__ in, u16* __restrict__ out, int R, int C,
    size_t inStride, size_t outStride) {
  __shared__ float tile[32][33];
  const float* ip = in + (size_t)blockIdx.z * inStride;
  u16* op = out + (size_t)blockIdx.z * outStride;
  const int c0 = blockIdx.x * 32, r0 = blockIdx.y * 32;
  const int tx = threadIdx.x & 31, ty = threadIdx.x >> 5;
#pragma unroll
  for (int p = 0; p < 4; ++p)
    tile[ty + p * 8][tx] = ip[(size_t)(r0 + ty + p * 8) * C + c0 + tx];
  __syncthreads();
#pragma unroll
  for (int p = 0; p < 4; ++p)
    op[(size_t)(c0 + ty + p * 8) * R + r0 + tx] = f2b(tile[tx][ty + p * 8]);
}

__global__ __launch_bounds__(256) void k_colsum(
    const u16* __restrict__ encvt, float* __restrict__ colsum) {
  const int row = blockIdx.x * 4 + (threadIdx.x >> 6);
  const int lane = threadIdx.x & 63;
  const u16* pr = encvt + (size_t)row * DD;
  float s = 0.f;
#pragma unroll
  for (int i = 0; i < 3; ++i) {
    ushort4 v = *(const ushort4*)&pr[(lane << 2) + i * 256];
    s += b2f(v.x) + b2f(v.y) + b2f(v.z) + b2f(v.w);
  }
#pragma unroll
  for (int off = 32; off; off >>= 1) s += __shfl_xor(s, off);
  if (lane == 0) colsum[row] = s;
}

// ---------------------------------------------------------------------------
// K1: latent = X16 @ ENCT[h]^T; relu; rope -> QR16 [b][h][t][n] AND
// QRT16 [b][h][n][t].  M=4096, N=256, K=768 per head.
// ---------------------------------------------------------------------------
__global__ __launch_bounds__(256) void k1_encode(
    const u16* __restrict__ x16, const u16* __restrict__ enct,
    u16* __restrict__ qr16, u16* __restrict__ qrt16) {
  const int h = blockIdx.z;
  const int m0 = blockIdx.x * 128, n0 = blockIdx.y * 128;
  GEMM_PROLOGUE();
  PIPELINED_K_LOOP(x16 + (size_t)m0 * DD, DD,
                   enct + ((size_t)h * NN + n0) * DD, DD, DD);
#pragma unroll
  for (int p = 0; p < 2; ++p) {
    __syncthreads();
    if (wr == p) {
#pragma unroll
      for (int i = 0; i < 4; ++i)
#pragma unroll
        for (int j = 0; j < 4; ++j) {
          const int n = n0 + wc * 64 + j * 16 + col16;
          const int q = n & ~1;
          const float freq = exp2f((float)q * -0.0625f) * 0.15915494309189535f;
          float rv[4], pv[4];
#pragma unroll
          for (int r = 0; r < 4; ++r) rv[r] = fmaxf(acc[i][j][r], 0.f);
#pragma unroll
          for (int r = 0; r < 4; ++r) pv[r] = __shfl_xor(rv[r], 1);
#pragma unroll
          for (int r = 0; r < 4; ++r) {
            const int lr = i * 16 + quad * 4 + r;
            const int t = (m0 + p * 64 + lr) & (TT - 1);
            float phase = (float)t * freq;
            float ph = (phase - floorf(phase)) * 6.283185307179586f;
            float s = __sinf(ph), c = __cosf(ph);
            float o = (n & 1) ? (rv[r] * c + pv[r] * s) : (rv[r] * c - pv[r] * s);
            smem[lr * 128 + wc * 64 + j * 16 + col16] = f2b(o);
          }
        }
    }
    __syncthreads();
    const int m = m0 + p * 64;
    const int b = m >> 11, tb = m & (TT - 1);
    const size_t sl = (size_t)(b * NHH + h);
    copy_out64(smem, qr16 + (sl * TT + tb) * NN + n0, NN, tid);
    // transposed copy: QRT16[sl][n][t] = tile[t][n]
#pragma unroll
    for (int s = 0; s < 4; ++s) {
      const int off = (s * 256 + tid) * 8;
      const int nr = off >> 6, tc = off & 63;
      u16 vals[8];
#pragma unroll
      for (int k = 0; k < 8; ++k) vals[k] = smem[(tc + k) * 128 + nr];
      *(u16x8*)&qrt16[(sl * NN + n0 + nr) * TT + tb + tc] = *(u16x8*)vals;
    }
  }
}

// ---------------------------------------------------------------------------
// kS: block-diagonal band of S = QR QR^T (strict lower), 40 tiles/slice.
// SB (group-local) [gs][TT][CH], sc = s - 512*(t/512).
// ---------------------------------------------------------------------------
__global__ __launch_bounds__(256) void kS_band(
    const u16* __restrict__ qr16, u16* __restrict__ sb, int bh0) {
  const int z = blockIdx.y;                  // group-local slice
  const int bh = bh0 + z;
  const int cc = blockIdx.x / 10, rr = blockIdx.x % 10;
  int i = (int)((sqrtf(8.f * rr + 1.f) - 1.f) * 0.5f);
  while ((i + 1) * (i + 2) / 2 <= rr) ++i;
  while (i * (i + 1) / 2 > rr) --i;
  const int j = rr - i * (i + 1) / 2;
  const int t0 = (cc * 4 + i) * 128;
  const int s0 = cc * CH + j * 128;
  const u16* q = qr16 + (size_t)bh * TT * NN;
  GEMM_PROLOGUE();
  PIPELINED_K_LOOP(q + (size_t)t0 * NN, NN, q + (size_t)s0 * NN, NN, NN);
  const bool diag = (i == j);
#pragma unroll
  for (int p = 0; p < 2; ++p) {
    __syncthreads();
    if (wr == p) {
#pragma unroll
      for (int ii = 0; ii < 4; ++ii)
#pragma unroll
        for (int jj = 0; jj < 4; ++jj) {
          const int s = s0 + wc * 64 + jj * 16 + col16;
#pragma unroll
          for (int r = 0; r < 4; ++r) {
            const int lr = ii * 16 + quad * 4 + r;
            const int t = t0 + p * 64 + lr;
            float v = acc[ii][jj][r];
            if (diag && s >= t) v = 0.f;
            smem[lr * 128 + wc * 64 + jj * 16 + col16] = f2b(v);
          }
        }
    }
    __syncthreads();
    copy_out64(smem, sb + ((size_t)z * TT + t0 + p * 64) * CH + j * 128, CH, tid);
  }
}

// ---------------------------------------------------------------------------
// kB_all: ONE launch. Each block owns a 64(d) x 128(n) tile of H and runs
// K = 0..1536 with fp32 accumulators, writing bf16 snapshot H16[z][c] at each
// chunk boundary (c = 0,1,2). Grid (12, 2, gs).
// Double-buffered counted-vmcnt pipeline (3 async16/thread/step -> vmcnt(3)).
// LDS: 2 x (A 2048 + B 4096) u16 dbuf (24KB) + 8192 u16 snapshot scratch.
// ---------------------------------------------------------------------------
__global__ __launch_bounds__(256) void kB_all(
    const u16* __restrict__ xt16, const u16* __restrict__ qrt16,
    u16* __restrict__ h16, int bh0) {
  __shared__ __attribute__((aligned(16))) u16 sm[20480];
  u16* buf0 = sm;            // A at +0 (64x32), B at +2048 (128x32)
  u16* buf1 = sm + 6144;
  u16* snap = sm + 12288;    // 64x128 u16
  const int tid = threadIdx.x;
  const int w = tid >> 6, lane = tid & 63;
  const int m16 = lane & 15, quad = lane >> 4;
  const int z = blockIdx.z;
  const int bh = bh0 + z, b = bh / NHH;
  const int d0 = blockIdx.x * 64, n0 = blockIdx.y * 128;
  f32x4 acc[4][2];
#pragma unroll
  for (int i = 0; i < 4; ++i)
#pragma unroll
    for (int j = 0; j < 2; ++j) acc[i][j] = (f32x4){0.f, 0.f, 0.f, 0.f};
  const u16* Ab = xt16 + ((size_t)b * DD + d0) * TT;
  const u16* Bb = qrt16 + ((size_t)bh * NN + n0) * TT;
  for (int c = 0; c < 3; ++c) {
    const int kbase = c * CH;
    stage64x32(Ab + kbase, TT, buf0, tid);
    stage128x32(Bb + kbase, TT, buf0 + 2048, tid);
    for (int s = 0; s < CH / 32; ++s) {
      u16* cb = (s & 1) ? buf1 : buf0;
      u16* nb = (s & 1) ? buf0 : buf1;
      if (s + 1 < CH / 32) {
        const int kn = kbase + (s + 1) * 32;
        stage64x32(Ab + kn, TT, nb, tid);
        stage128x32(Bb + kn, TT, nb + 2048, tid);
        asm volatile("s_waitcnt vmcnt(3)" ::: "memory");
      } else {
        asm volatile("s_waitcnt vmcnt(0)" ::: "memory");
      }
      __builtin_amdgcn_s_barrier();
      __builtin_amdgcn_sched_barrier(0);
      bf16x8 a[4], bb[2];
#pragma unroll
      for (int i = 0; i < 4; ++i)
        a[i] = *(const bf16x8*)&cb[(i * 16 + m16) * 32 + quad * 8];
#pragma unroll
      for (int j = 0; j < 2; ++j)
        bb[j] = *(const bf16x8*)&cb[2048 + (w * 32 + j * 16 + m16) * 32 + quad * 8];
#pragma unroll
      for (int i = 0; i < 4; ++i)
#pragma unroll
        for (int j = 0; j < 2; ++j)
          acc[i][j] = __builtin_amdgcn_mfma_f32_16x16x32_bf16(a[i], bb[j], acc[i][j], 0, 0, 0);
      __builtin_amdgcn_sched_barrier(0);
      __builtin_amdgcn_s_barrier();
    }
    // snapshot H16[z][c]: restage 64x128 fp32->bf16 via LDS, coalesced store
#pragma unroll
    for (int i = 0; i < 4; ++i)
#pragma unroll
      for (int j = 0; j < 2; ++j)
#pragma unroll
        for (int r = 0; r < 4; ++r)
          snap[(i * 16 + quad * 4 + r) * 128 + w * 32 + j * 16 + m16] =
              f2b(acc[i][j][r]);
    __syncthreads();
    u16* hd = h16 + (size_t)(z * 3 + c) * DD * NN;
#pragma unroll
    for (int s4 = 0; s4 < 4; ++s4) {
      const int off = (s4 * 256 + tid) * 8;
      const int row = off >> 7, col = off & 127;
      *(u16x8*)&hd[(size_t)(d0 + row) * NN + n0 + col] = *(const u16x8*)&snap[off];
    }
    __syncthreads();
  }
}

// ---------------------------------------------------------------------------
// kA: 128x128 output, unified panel-pipelined K sequence:
//   panels 0..3 (if c>0): QR[t-tile] @ H16[z][c-1]^T  (K=256)
//   panels after: for j<=it, SB tile @ XT16 (K=128 each, 2 panels/j)
// Double-buffered LDS (64KB), counted vmcnt(8), raw barriers.
// 1D grid of 96*gs blocks with bijective chunked XCD swizzle (T1): each XCD
// gets a contiguous (z,tt,d) range so the 6 d-blocks sharing QR/SB/H panels
// hit the same per-XCD L2 instead of re-fetching from HBM.
// LPT: tt order descending by work within each chunk.
// ---------------------------------------------------------------------------
__device__ static const int TTORD[16] = {15, 11, 7, 14, 10, 6, 13, 9,
                                         5, 3, 12, 8, 4, 2, 1, 0};

__global__ __launch_bounds__(256) void kA_attn(
    const u16* __restrict__ qr16, const u16* __restrict__ h16,
    const u16* __restrict__ sb, const u16* __restrict__ xt16,
    u16* __restrict__ ykv16, int bh0) {
  __shared__ __attribute__((aligned(16))) u16 smem[32768];  // 2 x 32KB buffers
  const int tid = threadIdx.x;
  const int w = tid >> 6, lane = tid & 63;
  const int wr = w >> 1, wc = w & 1;
  const int col16 = lane & 15, quad = lane >> 4;
  // chunked XCD swizzle: HW round-robins bid%8 across XCDs; map each
  // residue class to a contiguous logical range (bijective, nwg%8==0 here).
  const int nwg = gridDim.x;
  const int bid = blockIdx.x;
  const int qq = nwg >> 3, r8 = nwg & 7;
  const int xcd = bid & 7, pos = bid >> 3;
  const int wg = (xcd < r8 ? xcd * (qq + 1) : r8 * (qq + 1) + (xcd - r8) * qq) + pos;
  const int z = wg / 96;
  const int tt = TTORD[(wg / 6) & 15];       // LPT within chunk
  const int d0 = (wg % 6) * 128;
  const int bh = bh0 + z, b = bh / NHH;
  const int c = tt >> 2, it = tt & 3;
  const int t0 = tt * 128;
  f32x4 acc[4][4];
#pragma unroll
  for (int i = 0; i < 4; ++i)
#pragma unroll
    for (int j = 0; j < 4; ++j) acc[i][j] = (f32x4){0.f, 0.f, 0.f, 0.f};

  const int c4 = (c > 0) ? 4 : 0;
  const int nP = c4 + (it + 1) * 2;          // BK=64 panels total
  const u16* hs = h16 + ((size_t)(z * 3 + (c > 0 ? c - 1 : 0)) * DD + d0) * NN;
  const u16* qb = qr16 + ((size_t)bh * TT + t0) * NN;
  const u16* sbb = sb + ((size_t)z * TT + t0) * CH;
  const u16* xb = xt16 + ((size_t)b * DD + d0) * TT + c * CH;

  // Stage panel p (A: 128x64 as two 128x32, B likewise) into buf[0..16383].
#define KA_STAGE(buf, p)                                                  \
  {                                                                       \
    const u16 *pa_, *pb_; size_t la_, lb_;                                \
    if ((p) < c4) {                                                       \
      pa_ = qb + (p) * 64; la_ = NN;                                      \
      pb_ = hs + (p) * 64; lb_ = NN;                                      \
    } else {                                                              \
      const int q_ = (p) - c4;                                            \
      const int j_ = q_ >> 1, kk_ = (q_ & 1) << 6;                        \
      pa_ = sbb + j_ * 128 + kk_; la_ = CH;                               \
      pb_ = xb + j_ * 128 + kk_; lb_ = TT;                                \
    }                                                                     \
    stage128x32(pa_, la_, (buf), tid);                                    \
    stage128x32(pa_ + 32, la_, (buf) + 4096, tid);                        \
    stage128x32(pb_, lb_, (buf) + 8192, tid);                             \
    stage128x32(pb_ + 32, lb_, (buf) + 12288, tid);                       \
  }

  u16* bufA = smem;
  u16* bufB = smem + 16384;
  KA_STAGE(bufA, 0);
  for (int p = 0; p < nP; ++p) {
    u16* cb = (p & 1) ? bufB : bufA;
    u16* nb = (p & 1) ? bufA : bufB;
    if (p + 1 < nP) {
      KA_STAGE(nb, p + 1);
      // 8 async16/thread just issued for p+1: allow them to stay in flight,
      // wait only for panel p's 8 (the oldest) to have landed.
      asm volatile("s_waitcnt vmcnt(8)" ::: "memory");
    } else {
      asm volatile("s_waitcnt vmcnt(0)" ::: "memory");
    }
    __builtin_amdgcn_s_barrier();            // publish panel p across waves
    __builtin_amdgcn_sched_barrier(0);       // pin reads/MFMAs after barrier
    mfma_step(cb, cb + 8192, wr, wc, lane, acc);
    mfma_step(cb + 4096, cb + 12288, wr, wc, lane, acc);
    __builtin_amdgcn_sched_barrier(0);       // pin reads/MFMAs before barrier
    __builtin_amdgcn_s_barrier();            // reads of cb done before overwrite
  }
#undef KA_STAGE

#pragma unroll
  for (int p = 0; p < 2; ++p) {
    __syncthreads();
    if (wr == p) {
#pragma unroll
      for (int i = 0; i < 4; ++i)
#pragma unroll
        for (int j = 0; j < 4; ++j)
#pragma unroll
          for (int r = 0; r < 4; ++r) {
            const int lr = i * 16 + quad * 4 + r;
            smem[lr * 128 + wc * 64 + j * 16 + col16] = f2b(acc[i][j][r]);
          }
    }
    __syncthreads();
    copy_out64(smem, ykv16 + ((size_t)z * TT + t0 + p * 64) * DD + d0, DD, tid);
  }
}

// ---------------------------------------------------------------------------
// K3: per-row mean/rstd of group-local ykv16 (bf16 rows of 768). 1 wave/row.
// ---------------------------------------------------------------------------
__global__ __launch_bounds__(256) void k3_stats(
    const u16* __restrict__ ykv16, float* __restrict__ mu, float* __restrict__ rs) {
  const int row = blockIdx.x * 4 + (threadIdx.x >> 6);
  const int lane = threadIdx.x & 63;
  const u16* p = ykv16 + (size_t)row * DD;
  float sum = 0.f, sq = 0.f;
#pragma unroll
  for (int i = 0; i < 3; ++i) {
    ushort4 v = *(const ushort4*)&p[(lane << 2) + i * 256];
    float f0 = b2f(v.x), f1 = b2f(v.y), f2 = b2f(v.z), f3 = b2f(v.w);
    sum += f0 + f1 + f2 + f3;
    sq += f0 * f0 + f1 * f1 + f2 * f2 + f3 * f3;
  }
#pragma unroll
  for (int off = 32; off; off >>= 1) {
    sum += __shfl_xor(sum, off);
    sq += __shfl_xor(sq, off);
  }
  if (lane == 0) {
    float m = sum * (1.f / 768.f);
    float v = sq * (1.f / 768.f) - m * m;
    mu[row] = m;
    rs[row] = rsqrtf(v + 1e-5f);
  }
}

// ---------------------------------------------------------------------------
// K4: raw GEMM ykv16 @ ENCVT[h]^T with LN as epilogue affine; xs via inverse
// rope of QR16; out2 = xs*ys (fp32); XY (bf16) written IN PLACE into QR16's
// storage (reads of QR complete behind a barrier before the writes).
// ---------------------------------------------------------------------------
__global__ __launch_bounds__(256) void k4_xy(
    const u16* __restrict__ ykv16, const u16* __restrict__ encvt,
    u16* __restrict__ qrxy, const float* __restrict__ mu,
    const float* __restrict__ rs, const float* __restrict__ colsum,
    float* __restrict__ out2, int bh0) {
  const int z = blockIdx.z;
  const int bh = bh0 + z, h = bh % NHH;
  const int t0 = blockIdx.x * 128, n0 = blockIdx.y * 128;
  GEMM_PROLOGUE();
  PIPELINED_K_LOOP(ykv16 + ((size_t)z * TT + t0) * DD, DD,
                   encvt + ((size_t)h * NN + n0) * DD, DD, DD);
#pragma unroll
  for (int p = 0; p < 2; ++p) {
    __syncthreads();
    if (wr == p) {
#pragma unroll
      for (int i = 0; i < 4; ++i)
#pragma unroll
        for (int j = 0; j < 4; ++j) {
          const int n = n0 + wc * 64 + j * 16 + col16;
          const int qn = n & ~1;
          const float freq = exp2f((float)qn * -0.0625f) * 0.15915494309189535f;
          const float cs = colsum[h * NN + n];
#pragma unroll
          for (int r = 0; r < 4; ++r) {
            const int lr = i * 16 + quad * 4 + r;
            const int t = t0 + p * 64 + lr;
            const int lrow = z * TT + t;
            const float muv = mu[lrow], rsv = rs[lrow];
            float ys = fmaxf(rsv * acc[i][j][r] - rsv * muv * cs, 0.f);
            const size_t gi = ((size_t)bh * TT + t) * NN + n;
            float qs = b2f(qrxy[gi]);
            float qp = b2f(qrxy[gi ^ 1]);
            float phase = (float)t * freq;
            float ph = (phase - floorf(phase)) * 6.283185307179586f;
            float s = __sinf(ph), c2 = __cosf(ph);
            float xs = (n & 1) ? (qs * c2 - qp * s) : (qs * c2 + qp * s);
            float val = ys * xs;
            out2[gi] = val;
            smem[lr * 128 + wc * 64 + j * 16 + col16] = f2b(val);
          }
        }
    }
    __syncthreads();
    copy_out64(smem, qrxy + ((size_t)bh * TT + t0 + p * 64) * NN + n0, NN, tid);
  }
}

// ---------------------------------------------------------------------------
// K5: ymlp = flat(XY) @ DECT^T.  M=4096, N=768, K=3072.  64x64 tiles
// (768 blocks); A gathered from XY's [b][h][t][n] layout (in QR16 storage).
// Double-buffered counted-vmcnt pipeline (2 async16/thread/step -> vmcnt(2)).
// ---------------------------------------------------------------------------
__global__ __launch_bounds__(256) void k5_mlp(
    const u16* __restrict__ xyq, const u16* __restrict__ dect,
    float* __restrict__ ymlp) {
  __shared__ __attribute__((aligned(16))) u16 sm[8192];
  u16* buf0 = sm;           // A at +0 (64x32), B at +2048 (64x32)
  u16* buf1 = sm + 4096;
  const int tid = threadIdx.x;
  const int w = tid >> 6, lane = tid & 63;
  const int wr = w >> 1, wc = w & 1;
  const int m16 = lane & 15, quad = lane >> 4;
  const int m0 = blockIdx.x * 64, d0 = blockIdx.y * 64;
  f32x4 acc[2][2];
#pragma unroll
  for (int i = 0; i < 2; ++i)
#pragma unroll
    for (int j = 0; j < 2; ++j) acc[i][j] = (f32x4){0.f, 0.f, 0.f, 0.f};
  const int ar = w * 16 + (lane >> 2);      // A row within 64-tile
  const int m = m0 + ar;
  const int b = m >> 11, t = m & (TT - 1);
  const int kc = (lane & 3) << 3;
  const int NK = NHH * NN / 32;             // 96 steps
  // prologue: step 0
  async16(xyq + ((size_t)(b * NHH) * TT + t) * NN + kc, buf0 + w * 512);
  stage64x32(dect + (size_t)d0 * (NHH * NN), NHH * NN, buf0 + 2048, tid);
  for (int s = 0; s < NK; ++s) {
    u16* cb = (s & 1) ? buf1 : buf0;
    u16* nb = (s & 1) ? buf0 : buf1;
    if (s + 1 < NK) {
      const int k0 = (s + 1) * 32;
      const int hh = k0 >> 8;
      const int kk = (k0 & 255) + kc;
      async16(xyq + ((size_t)(b * NHH + hh) * TT + t) * NN + kk, nb + w * 512);
      stage64x32(dect + (size_t)d0 * (NHH * NN) + k0, NHH * NN, nb + 2048, tid);
      asm volatile("s_waitcnt vmcnt(2)" ::: "memory");
    } else {
      asm volatile("s_waitcnt vmcnt(0)" ::: "memory");
    }
    __builtin_amdgcn_s_barrier();
    __builtin_amdgcn_sched_barrier(0);
    bf16x8 a[2], bb[2];
#pragma unroll
    for (int i = 0; i < 2; ++i)
      a[i] = *(const bf16x8*)&cb[(wr * 32 + i * 16 + m16) * 32 + quad * 8];
#pragma unroll
    for (int j = 0; j < 2; ++j)
      bb[j] = *(const bf16x8*)&cb[2048 + (wc * 32 + j * 16 + m16) * 32 + quad * 8];
#pragma unroll
    for (int i = 0; i < 2; ++i)
#pragma unroll
      for (int j = 0; j < 2; ++j)
        acc[i][j] = __builtin_amdgcn_mfma_f32_16x16x32_bf16(a[i], bb[j], acc[i][j], 0, 0, 0);
    __builtin_amdgcn_sched_barrier(0);
    __builtin_amdgcn_s_barrier();
  }
#pragma unroll
  for (int i = 0; i < 2; ++i)
#pragma unroll
    for (int j = 0; j < 2; ++j) {
      const int d = d0 + wc * 32 + j * 16 + m16;
#pragma unroll
      for (int r = 0; r < 4; ++r) {
        const int mm = m0 + wr * 32 + i * 16 + quad * 4 + r;
        ymlp[(size_t)mm * DD + d] = acc[i][j][r];
      }
    }
}

// ---------------------------------------------------------------------------
// K6: y = ln(ymlp)*sqrt(0.1/(ra+1e-6))*scale; out1 = ln(x+y). Block per row.
// ymlp aliases out1 (in-place per row).
// ---------------------------------------------------------------------------
__global__ __launch_bounds__(256) void k6_final(
    const float* __restrict__ ymlp, const float* __restrict__ x,
    const float* __restrict__ scale, const float* __restrict__ ra,
    float* __restrict__ out1) {
  const int row = blockIdx.x;
  const int tid = threadIdx.x;
  const int wid = tid >> 6, lane = tid & 63;
  __shared__ float red[8];
  float v[3];
  float sum = 0.f, sq = 0.f;
#pragma unroll
  for (int j = 0; j < 3; ++j) {
    v[j] = ymlp[(size_t)row * DD + tid + j * 256];
    sum += v[j]; sq += v[j] * v[j];
  }
#pragma unroll
  for (int off = 32; off; off >>= 1) { sum += __shfl_xor(sum, off); sq += __shfl_xor(sq, off); }
  if (lane == 0) { red[wid] = sum; red[4 + wid] = sq; }
  __syncthreads();
  sum = red[0] + red[1] + red[2] + red[3];
  sq = red[4] + red[5] + red[6] + red[7];
  const float m1 = sum * (1.f / 768.f);
  const float r1 = rsqrtf(sq * (1.f / 768.f) - m1 * m1 + 1e-5f);
  float z[3];
  float sum2 = 0.f, sq2 = 0.f;
#pragma unroll
  for (int j = 0; j < 3; ++j) {
    const int d = tid + j * 256;
    float y = (v[j] - m1) * r1 * sqrtf(0.1f / (ra[d] + 1e-6f)) * scale[d];
    z[j] = x[(size_t)row * DD + d] + y;
    sum2 += z[j]; sq2 += z[j] * z[j];
  }
  __syncthreads();
#pragma unroll
  for (int off = 32; off; off >>= 1) { sum2 += __shfl_xor(sum2, off); sq2 += __shfl_xor(sq2, off); }
  if (lane == 0) { red[wid] = sum2; red[4 + wid] = sq2; }
  __syncthreads();
  sum2 = red[0] + red[1] + red[2] + red[3];
  sq2 = red[4] + red[5] + red[6] + red[7];
  const float m2 = sum2 * (1.f / 768.f);
  const float r2 = rsqrtf(sq2 * (1.f / 768.f) - m2 * m2 + 1e-5f);
#pragma unroll
  for (int j = 0; j < 3; ++j)
    out1[(size_t)row * DD + tid + j * 256] = (z[j] - m2) * r2;
}

// ---------------------------------------------------------------------------
extern "C" void kernel_launch(void* const* d_in, const int* in_sizes, int n_in,
                              void* d_out, int out_size, void* d_ws, size_t ws_size,
                              hipStream_t stream) {
  const float* x = (const float*)d_in[0];
  const float* enc = (const float*)d_in[1];
  const float* encv = (const float*)d_in[2];
  const float* dec = (const float*)d_in[3];
  const float* scale = (const float*)d_in[4];
  const float* ra = (const float*)d_in[5];
  float* out1 = (float*)d_out;
  float* out2 = out1 + (size_t)BB * TT * DD;
  float* ymlp = out1;                         // k5 scratch, k6 in-place

  const int NS = BB * NHH;  // 24 slices
  unsigned char* p = (unsigned char*)d_ws;
  u16* X16 = (u16*)p;    p += (size_t)BB * TT * DD * 2;
  u16* XT16 = (u16*)p;   p += (size_t)BB * DD * TT * 2;
  u16* ENCT = (u16*)p;   p += (size_t)NHH * NN * DD * 2;
  u16* ENCVT = (u16*)p;  p += (size_t)NHH * NN * DD * 2;
  u16* DECT = (u16*)p;   p += (size_t)DD * NHH * NN * 2;
  u16* QR16 = (u16*)p;   p += (size_t)NS * TT * NN * 2;   // holds QR, then XY
  u16* QRT16 = (u16*)p;  p += (size_t)NS * NN * TT * 2;
  float* COLSUM = (float*)p; p += (size_t)NHH * NN * 4;
  // Adaptive, BALANCED per-slice attention pool:
  //   SB (TT*CH bf16) + H16 (3 snapshots DD*NN bf16) + YKV16 (TT*DD bf16)
  //   + MU/RS (TT f32 each)
  const size_t SLICE_B = (size_t)TT * CH * 2 + 3 * (size_t)DD * NN * 2 +
                         (size_t)TT * DD * 2 + (size_t)TT * 8;
  size_t fixed = (size_t)(p - (unsigned char*)d_ws);
  size_t rem = (ws_size > fixed) ? ws_size - fixed : 0;
  int GSmax = (int)(rem / SLICE_B);
  if (GSmax < 1) GSmax = 1;
  if (GSmax > NS) GSmax = NS;
  const int ngrp = (NS + GSmax - 1) / GSmax;
  const int GS = (NS + ngrp - 1) / ngrp;     // balanced groups
  u16* SB = (u16*)p;     p += (size_t)GS * TT * CH * 2;
  u16* H16 = (u16*)p;    p += (size_t)GS * 3 * DD * NN * 2;
  u16* YKV16 = (u16*)p;  p += (size_t)GS * TT * DD * 2;
  float* MU = (float*)p; p += (size_t)GS * TT * 4;
  float* RS = (float*)p; p += (size_t)GS * TT * 4;

  // One-time conversions / transposes
  cvt_bf16<<<dim3((BB * TT * DD) / 1024), 256, 0, stream>>>(x, X16, (size_t)BB * TT * DD / 4);
  tcvt_bf16<<<dim3(DD / 32, TT / 32, BB), 256, 0, stream>>>(
      x, XT16, TT, DD, (size_t)TT * DD, (size_t)DD * TT);
  tcvt_bf16<<<dim3(NN / 32, DD / 32, NHH), 256, 0, stream>>>(
      enc, ENCT, DD, NN, (size_t)DD * NN, (size_t)NN * DD);
  tcvt_bf16<<<dim3(NN / 32, DD / 32, NHH), 256, 0, stream>>>(
      encv, ENCVT, DD, NN, (size_t)DD * NN, (size_t)NN * DD);
  tcvt_bf16<<<dim3(DD / 32, (NHH * NN) / 32, 1), 256, 0, stream>>>(
      dec, DECT, NHH * NN, DD, 0, 0);
  k_colsum<<<dim3(NHH * NN / 4), 256, 0, stream>>>(ENCVT, COLSUM);

  k1_encode<<<dim3(BB * TT / 128, NN / 128, NHH), 256, 0, stream>>>(
      X16, ENCT, QR16, QRT16);

  for (int bh0 = 0; bh0 < NS; bh0 += GS) {
    const int gs = imin(GS, NS - bh0);
    kS_band<<<dim3(40, gs), 256, 0, stream>>>(QR16, SB, bh0);
    kB_all<<<dim3(DD / 64, NN / 128, gs), 256, 0, stream>>>(
        XT16, QRT16, H16, bh0);
    kA_attn<<<dim3(96 * gs), 256, 0, stream>>>(
        QR16, H16, SB, XT16, YKV16, bh0);
    k3_stats<<<dim3(gs * TT / 4), 256, 0, stream>>>(YKV16, MU, RS);
    k4_xy<<<dim3(TT / 128, NN / 128, gs), 256, 0, stream>>>(
        YKV16, ENCVT, QR16, MU, RS, COLSUM, out2, bh0);
  }

  k5_mlp<<<dim3(BB * TT / 64, DD / 64), 256, 0, stream>>>(QR16, DECT, ymlp);
  k6_final<<<dim3(BB * TT), 256, 0, stream>>>(ymlp, x, scale, ra, out1);
}

// Round 3
// 402.297 us; speedup vs baseline: 1.2098x; 1.0184x over previous
//
#include <hip/hip_runtime.h>
#include <math.h>

#define TT 2048
#define DD 768
#define NN 256
#define NHH 12
#define BB 2
#define CH 512           // attention chunk (4 chunks of 4 x 128-tiles)

typedef unsigned short u16;
typedef __attribute__((ext_vector_type(8))) short bf16x8;
typedef __attribute__((ext_vector_type(8))) unsigned short u16x8;
typedef __attribute__((ext_vector_type(4))) float f32x4;

static inline int imin(int a, int b) { return a < b ? a : b; }

__device__ __forceinline__ u16 f2b(float f) {
  union { float f; unsigned u; } a; a.f = f;
  unsigned r = a.u + 0x7FFF + ((a.u >> 16) & 1);
  return (u16)(r >> 16);
}
__device__ __forceinline__ float b2f(u16 h) {
  union { unsigned u; float f; } a; a.u = ((unsigned)h) << 16;
  return a.f;
}

__device__ __forceinline__ void async16(const void* g, void* l) {
  __builtin_amdgcn_global_load_lds(
      (const __attribute__((address_space(1))) unsigned*)g,
      (__attribute__((address_space(3))) unsigned*)l, 16, 0, 0);
}

// Stage a 128x32 bf16 tile (row-major, ld in elements) into LDS [128][32].
__device__ __forceinline__ void stage128x32(
    const u16* __restrict__ gbase, size_t ld, u16* lds, int tid) {
  const int w = tid >> 6, l = tid & 63;
  const int r = l >> 2, kc = (l & 3) << 3;
#pragma unroll
  for (int q = 0; q < 2; ++q) {
    const int row0 = w * 32 + q * 16;
    async16(gbase + (size_t)(row0 + r) * ld + kc, lds + row0 * 32);
  }
}

// Stage a 64x32 bf16 tile into LDS [64][32]. One async16 per thread.
__device__ __forceinline__ void stage64x32(
    const u16* __restrict__ gbase, size_t ld, u16* lds, int tid) {
  const int w = tid >> 6, l = tid & 63;
  const int r = w * 16 + (l >> 2), kc = (l & 3) << 3;
  async16(gbase + (size_t)r * ld + kc, lds + w * 512);
}

// 16 MFMAs of one BK=32 step; wave (wr,wc) computes 64x64 of the 128x128 tile.
__device__ __forceinline__ void mfma_step(
    const u16* As, const u16* Bs, int wr, int wc, int lane, f32x4 acc[4][4]) {
  const int m16 = lane & 15, quad = lane >> 4;
  bf16x8 a[4], b[4];
#pragma unroll
  for (int i = 0; i < 4; ++i)
    a[i] = *(const bf16x8*)&As[(wr * 64 + i * 16 + m16) * 32 + quad * 8];
#pragma unroll
  for (int j = 0; j < 4; ++j)
    b[j] = *(const bf16x8*)&Bs[(wc * 64 + j * 16 + m16) * 32 + quad * 8];
#pragma unroll
  for (int i = 0; i < 4; ++i)
#pragma unroll
    for (int j = 0; j < 4; ++j)
      acc[i][j] = __builtin_amdgcn_mfma_f32_16x16x32_bf16(a[i], b[j], acc[i][j], 0, 0, 0);
}

// copy a full 128x128 u16 tile from LDS (row-major) to global rows of ld.
__device__ __forceinline__ void copy_out128(
    const u16* buf, u16* g, size_t ld, int tid) {
#pragma unroll
  for (int s = 0; s < 8; ++s) {
    const int off = (s * 256 + tid) * 8;
    const int row = off >> 7, col = off & 127;
    *(u16x8*)&g[(size_t)row * ld + col] = *(const u16x8*)&buf[off];
  }
}

#define GEMM_PROLOGUE()                                            \
  __shared__ __attribute__((aligned(16))) u16 smem[16384];         \
  const int tid = threadIdx.x;                                     \
  const int w = tid >> 6, lane = tid & 63;                         \
  const int wr = w >> 1, wc = w & 1;                               \
  const int col16 = lane & 15, quad = lane >> 4;                   \
  f32x4 acc[4][4];                                                 \
  _Pragma("unroll") for (int i = 0; i < 4; ++i)                    \
  _Pragma("unroll") for (int j = 0; j < 4; ++j)                    \
      acc[i][j] = (f32x4){0.f, 0.f, 0.f, 0.f};

// Double-buffered, counted-vmcnt pipelined K loop (T3-lite 2-phase).
#define PIPELINED_K_LOOP(ABASE, ALD, BBASE, BLD, KTOT)                      \
  {                                                                         \
    u16* bA_ = smem; u16* bB_ = smem + 8192;                                \
    stage128x32((ABASE), (ALD), bA_, tid);                                  \
    stage128x32((BBASE), (BLD), bA_ + 4096, tid);                           \
    const int nk_ = (KTOT) / 32;                                            \
    for (int kp_ = 0; kp_ < nk_; ++kp_) {                                   \
      u16* cb_ = (kp_ & 1) ? bB_ : bA_;                                     \
      u16* nb_ = (kp_ & 1) ? bA_ : bB_;                                     \
      if (kp_ + 1 < nk_) {                                                  \
        const int kn_ = (kp_ + 1) * 32;                                     \
        stage128x32((ABASE) + kn_, (ALD), nb_, tid);                        \
        stage128x32((BBASE) + kn_, (BLD), nb_ + 4096, tid);                 \
        asm volatile("s_waitcnt vmcnt(4)" ::: "memory");                    \
      } else {                                                              \
        asm volatile("s_waitcnt vmcnt(0)" ::: "memory");                    \
      }                                                                     \
      __builtin_amdgcn_s_barrier();                                         \
      __builtin_amdgcn_sched_barrier(0);                                    \
      mfma_step(cb_, cb_ + 4096, wr, wc, lane, acc);                        \
      __builtin_amdgcn_sched_barrier(0);                                    \
      __builtin_amdgcn_s_barrier();                                         \
    }                                                                       \
  }

// ---------------------------------------------------------------------------
__global__ __launch_bounds__(256) void cvt_bf16(
    const float* __restrict__ in, u16* __restrict__ out, size_t n4) {
  size_t i = ((size_t)blockIdx.x * 256 + threadIdx.x) * 4;
  if (i >= n4 * 4) return;
  float4 v = *(const float4*)&in[i];
  u16 o[4] = {f2b(v.x), f2b(v.y), f2b(v.z), f2b(v.w)};
  *(ushort4*)&out[i] = *(ushort4*)o;
}

__global__ __launch_bounds__(256) void tcvt_bf16(
    const float* __restrict__ in, u16* __restrict__ out, int R, int C,
    size_t inStride, size_t outStride) {
  __shared__ float tile[32][33];
  const float* ip = in + (size_t)blockIdx.z * inStride;
  u16* op = out + (size_t)blockIdx.z * outStride;
  const int c0 = blockIdx.x * 32, r0 = blockIdx.y * 32;
  const int tx = threadIdx.x & 31, ty = threadIdx.x >> 5;
#pragma unroll
  for (int p = 0; p < 4; ++p)
    tile[ty + p * 8][tx] = ip[(size_t)(r0 + ty + p * 8) * C + c0 + tx];
  __syncthreads();
#pragma unroll
  for (int p = 0; p < 4; ++p)
    op[(size_t)(c0 + ty + p * 8) * R + r0 + tx] = f2b(tile[tx][ty + p * 8]);
}

__global__ __launch_bounds__(256) void k_colsum(
    const u16* __restrict__ encvt, float* __restrict__ colsum) {
  const int row = blockIdx.x * 4 + (threadIdx.x >> 6);
  const int lane = threadIdx.x & 63;
  const u16* pr = encvt + (size_t)row * DD;
  float s = 0.f;
#pragma unroll
  for (int i = 0; i < 3; ++i) {
    ushort4 v = *(const ushort4*)&pr[(lane << 2) + i * 256];
    s += b2f(v.x) + b2f(v.y) + b2f(v.z) + b2f(v.w);
  }
#pragma unroll
  for (int off = 32; off; off >>= 1) s += __shfl_xor(s, off);
  if (lane == 0) colsum[row] = s;
}

// Precompute rope cos/sin table: CS[t*128 + n2] = {cos, sin} of
// 2*pi*frac(t * freq(2*n2)).  Bit-identical to the previous inline math.
__global__ __launch_bounds__(256) void k_cstab(float2* __restrict__ cs) {
  const int idx = blockIdx.x * 256 + threadIdx.x;   // t*128 + n2
  const int t = idx >> 7, n2 = idx & 127;
  const float freq = exp2f((float)(2 * n2) * -0.0625f) * 0.15915494309189535f;
  const float phase = (float)t * freq;
  const float ph = (phase - floorf(phase)) * 6.283185307179586f;
  cs[idx] = make_float2(__cosf(ph), __sinf(ph));
}

// ---------------------------------------------------------------------------
// K1: latent = X16 @ ENCT[h]^T; relu; rope -> QR16 [b][h][t][n] AND
// QRT16 [b][h][n][t].  M=4096, N=256, K=768 per head.
// Single-pass full-tile (32KB) epilogue; rope via CS table.
// ---------------------------------------------------------------------------
__global__ __launch_bounds__(256) void k1_encode(
    const u16* __restrict__ x16, const u16* __restrict__ enct,
    const float2* __restrict__ CS,
    u16* __restrict__ qr16, u16* __restrict__ qrt16) {
  const int h = blockIdx.z;
  const int m0 = blockIdx.x * 128, n0 = blockIdx.y * 128;
  GEMM_PROLOGUE();
  PIPELINED_K_LOOP(x16 + (size_t)m0 * DD, DD,
                   enct + ((size_t)h * NN + n0) * DD, DD, DD);
  __syncthreads();
#pragma unroll
  for (int i = 0; i < 4; ++i)
#pragma unroll
    for (int j = 0; j < 4; ++j) {
      const int n = n0 + wc * 64 + j * 16 + col16;
      float rv[4], pv[4];
#pragma unroll
      for (int r = 0; r < 4; ++r) rv[r] = fmaxf(acc[i][j][r], 0.f);
#pragma unroll
      for (int r = 0; r < 4; ++r) pv[r] = __shfl_xor(rv[r], 1);
#pragma unroll
      for (int r = 0; r < 4; ++r) {
        const int lrow = wr * 64 + i * 16 + quad * 4 + r;
        const int t = (m0 + lrow) & (TT - 1);
        const float2 cs = CS[t * 128 + (n >> 1)];
        const float o = (n & 1) ? (rv[r] * cs.x + pv[r] * cs.y)
                                : (rv[r] * cs.x - pv[r] * cs.y);
        smem[lrow * 128 + wc * 64 + j * 16 + col16] = f2b(o);
      }
    }
  __syncthreads();
  const int bq = m0 >> 11, tb = m0 & (TT - 1);
  const size_t sl = (size_t)(bq * NHH + h);
  copy_out128(smem, qr16 + (sl * TT + tb) * NN + n0, NN, tid);
  // transposed copy: QRT16[sl][n][t] = tile[t][n]
#pragma unroll
  for (int s = 0; s < 8; ++s) {
    const int off = (s * 256 + tid) * 8;
    const int nr = off >> 7, tc = off & 127;
    u16 vals[8];
#pragma unroll
    for (int k = 0; k < 8; ++k) vals[k] = smem[(tc + k) * 128 + nr];
    *(u16x8*)&qrt16[(sl * NN + n0 + nr) * TT + tb + tc] = *(u16x8*)vals;
  }
}

// ---------------------------------------------------------------------------
// kS: block-diagonal band of S = QR QR^T (strict lower), 40 tiles/slice.
// SB (group-local) [gs][TT][CH], sc = s - 512*(t/512).
// ---------------------------------------------------------------------------
__global__ __launch_bounds__(256) void kS_band(
    const u16* __restrict__ qr16, u16* __restrict__ sb, int bh0) {
  const int z = blockIdx.y;                  // group-local slice
  const int bh = bh0 + z;
  const int cc = blockIdx.x / 10, rr = blockIdx.x % 10;
  int i = (int)((sqrtf(8.f * rr + 1.f) - 1.f) * 0.5f);
  while ((i + 1) * (i + 2) / 2 <= rr) ++i;
  while (i * (i + 1) / 2 > rr) --i;
  const int j = rr - i * (i + 1) / 2;
  const int t0 = (cc * 4 + i) * 128;
  const int s0 = cc * CH + j * 128;
  const u16* q = qr16 + (size_t)bh * TT * NN;
  GEMM_PROLOGUE();
  PIPELINED_K_LOOP(q + (size_t)t0 * NN, NN, q + (size_t)s0 * NN, NN, NN);
  const bool diag = (i == j);
  __syncthreads();
#pragma unroll
  for (int ii = 0; ii < 4; ++ii)
#pragma unroll
    for (int jj = 0; jj < 4; ++jj) {
      const int s = s0 + wc * 64 + jj * 16 + col16;
#pragma unroll
      for (int r = 0; r < 4; ++r) {
        const int lrow = wr * 64 + ii * 16 + quad * 4 + r;
        const int t = t0 + lrow;
        float v = acc[ii][jj][r];
        if (diag && s >= t) v = 0.f;
        smem[lrow * 128 + wc * 64 + jj * 16 + col16] = f2b(v);
      }
    }
  __syncthreads();
  copy_out128(smem, sb + ((size_t)z * TT + t0) * CH + j * 128, CH, tid);
}

// ---------------------------------------------------------------------------
// kB_all: ONE launch. Each block owns a 64(d) x 128(n) tile of H and runs
// K = 0..1536 with fp32 accumulators, writing bf16 snapshot H16[z][c] at each
// chunk boundary (c = 0,1,2). Grid (12, 2, gs).
// Double-buffered counted-vmcnt pipeline (3 async16/thread/step -> vmcnt(3)).
// ---------------------------------------------------------------------------
__global__ __launch_bounds__(256) void kB_all(
    const u16* __restrict__ xt16, const u16* __restrict__ qrt16,
    u16* __restrict__ h16, int bh0) {
  __shared__ __attribute__((aligned(16))) u16 sm[20480];
  u16* buf0 = sm;            // A at +0 (64x32), B at +2048 (128x32)
  u16* buf1 = sm + 6144;
  u16* snap = sm + 12288;    // 64x128 u16
  const int tid = threadIdx.x;
  const int w = tid >> 6, lane = tid & 63;
  const int m16 = lane & 15, quad = lane >> 4;
  const int z = blockIdx.z;
  const int bh = bh0 + z, b = bh / NHH;
  const int d0 = blockIdx.x * 64, n0 = blockIdx.y * 128;
  f32x4 acc[4][2];
#pragma unroll
  for (int i = 0; i < 4; ++i)
#pragma unroll
    for (int j = 0; j < 2; ++j) acc[i][j] = (f32x4){0.f, 0.f, 0.f, 0.f};
  const u16* Ab = xt16 + ((size_t)b * DD + d0) * TT;
  const u16* Bb = qrt16 + ((size_t)bh * NN + n0) * TT;
  for (int c = 0; c < 3; ++c) {
    const int kbase = c * CH;
    stage64x32(Ab + kbase, TT, buf0, tid);
    stage128x32(Bb + kbase, TT, buf0 + 2048, tid);
    for (int s = 0; s < CH / 32; ++s) {
      u16* cb = (s & 1) ? buf1 : buf0;
      u16* nb = (s & 1) ? buf0 : buf1;
      if (s + 1 < CH / 32) {
        const int kn = kbase + (s + 1) * 32;
        stage64x32(Ab + kn, TT, nb, tid);
        stage128x32(Bb + kn, TT, nb + 2048, tid);
        asm volatile("s_waitcnt vmcnt(3)" ::: "memory");
      } else {
        asm volatile("s_waitcnt vmcnt(0)" ::: "memory");
      }
      __builtin_amdgcn_s_barrier();
      __builtin_amdgcn_sched_barrier(0);
      bf16x8 a[4], bb[2];
#pragma unroll
      for (int i = 0; i < 4; ++i)
        a[i] = *(const bf16x8*)&cb[(i * 16 + m16) * 32 + quad * 8];
#pragma unroll
      for (int j = 0; j < 2; ++j)
        bb[j] = *(const bf16x8*)&cb[2048 + (w * 32 + j * 16 + m16) * 32 + quad * 8];
#pragma unroll
      for (int i = 0; i < 4; ++i)
#pragma unroll
        for (int j = 0; j < 2; ++j)
          acc[i][j] = __builtin_amdgcn_mfma_f32_16x16x32_bf16(a[i], bb[j], acc[i][j], 0, 0, 0);
      __builtin_amdgcn_sched_barrier(0);
      __builtin_amdgcn_s_barrier();
    }
    // snapshot H16[z][c]: restage 64x128 fp32->bf16 via LDS, coalesced store
#pragma unroll
    for (int i = 0; i < 4; ++i)
#pragma unroll
      for (int j = 0; j < 2; ++j)
#pragma unroll
        for (int r = 0; r < 4; ++r)
          snap[(i * 16 + quad * 4 + r) * 128 + w * 32 + j * 16 + m16] =
              f2b(acc[i][j][r]);
    __syncthreads();
    u16* hd = h16 + (size_t)(z * 3 + c) * DD * NN;
#pragma unroll
    for (int s4 = 0; s4 < 4; ++s4) {
      const int off = (s4 * 256 + tid) * 8;
      const int row = off >> 7, col = off & 127;
      *(u16x8*)&hd[(size_t)(d0 + row) * NN + n0 + col] = *(const u16x8*)&snap[off];
    }
    __syncthreads();
  }
}

// ---------------------------------------------------------------------------
// kA: 128x128 output, unified panel-pipelined K sequence.
// 1D grid, bijective chunked XCD swizzle (T1) + LPT tt order.
// ---------------------------------------------------------------------------
__device__ static const int TTORD[16] = {15, 11, 7, 14, 10, 6, 13, 9,
                                         5, 3, 12, 8, 4, 2, 1, 0};

__global__ __launch_bounds__(256) void kA_attn(
    const u16* __restrict__ qr16, const u16* __restrict__ h16,
    const u16* __restrict__ sb, const u16* __restrict__ xt16,
    u16* __restrict__ ykv16, int bh0) {
  __shared__ __attribute__((aligned(16))) u16 smem[32768];  // 2 x 32KB buffers
  const int tid = threadIdx.x;
  const int w = tid >> 6, lane = tid & 63;
  const int wr = w >> 1, wc = w & 1;
  const int col16 = lane & 15, quad = lane >> 4;
  const int nwg = gridDim.x;
  const int bid = blockIdx.x;
  const int qq = nwg >> 3, r8 = nwg & 7;
  const int xcd = bid & 7, pos = bid >> 3;
  const int wg = (xcd < r8 ? xcd * (qq + 1) : r8 * (qq + 1) + (xcd - r8) * qq) + pos;
  const int z = wg / 96;
  const int tt = TTORD[(wg / 6) & 15];       // LPT within chunk
  const int d0 = (wg % 6) * 128;
  const int bh = bh0 + z, b = bh / NHH;
  const int c = tt >> 2, it = tt & 3;
  const int t0 = tt * 128;
  f32x4 acc[4][4];
#pragma unroll
  for (int i = 0; i < 4; ++i)
#pragma unroll
    for (int j = 0; j < 4; ++j) acc[i][j] = (f32x4){0.f, 0.f, 0.f, 0.f};

  const int c4 = (c > 0) ? 4 : 0;
  const int nP = c4 + (it + 1) * 2;          // BK=64 panels total
  const u16* hs = h16 + ((size_t)(z * 3 + (c > 0 ? c - 1 : 0)) * DD + d0) * NN;
  const u16* qb = qr16 + ((size_t)bh * TT + t0) * NN;
  const u16* sbb = sb + ((size_t)z * TT + t0) * CH;
  const u16* xb = xt16 + ((size_t)b * DD + d0) * TT + c * CH;

#define KA_STAGE(buf, p)                                                  \
  {                                                                       \
    const u16 *pa_, *pb_; size_t la_, lb_;                                \
    if ((p) < c4) {                                                       \
      pa_ = qb + (p) * 64; la_ = NN;                                      \
      pb_ = hs + (p) * 64; lb_ = NN;                                      \
    } else {                                                              \
      const int q_ = (p) - c4;                                            \
      const int j_ = q_ >> 1, kk_ = (q_ & 1) << 6;                        \
      pa_ = sbb + j_ * 128 + kk_; la_ = CH;                               \
      pb_ = xb + j_ * 128 + kk_; lb_ = TT;                                \
    }                                                                     \
    stage128x32(pa_, la_, (buf), tid);                                    \
    stage128x32(pa_ + 32, la_, (buf) + 4096, tid);                        \
    stage128x32(pb_, lb_, (buf) + 8192, tid);                             \
    stage128x32(pb_ + 32, lb_, (buf) + 12288, tid);                       \
  }

  u16* bufA = smem;
  u16* bufB = smem + 16384;
  KA_STAGE(bufA, 0);
  for (int p = 0; p < nP; ++p) {
    u16* cb = (p & 1) ? bufB : bufA;
    u16* nb = (p & 1) ? bufA : bufB;
    if (p + 1 < nP) {
      KA_STAGE(nb, p + 1);
      asm volatile("s_waitcnt vmcnt(8)" ::: "memory");
    } else {
      asm volatile("s_waitcnt vmcnt(0)" ::: "memory");
    }
    __builtin_amdgcn_s_barrier();            // publish panel p across waves
    __builtin_amdgcn_sched_barrier(0);
    mfma_step(cb, cb + 8192, wr, wc, lane, acc);
    mfma_step(cb + 4096, cb + 12288, wr, wc, lane, acc);
    __builtin_amdgcn_sched_barrier(0);
    __builtin_amdgcn_s_barrier();            // reads of cb done before overwrite
  }
#undef KA_STAGE

  __syncthreads();
#pragma unroll
  for (int i = 0; i < 4; ++i)
#pragma unroll
    for (int j = 0; j < 4; ++j)
#pragma unroll
      for (int r = 0; r < 4; ++r) {
        const int lrow = wr * 64 + i * 16 + quad * 4 + r;
        smem[lrow * 128 + wc * 64 + j * 16 + col16] = f2b(acc[i][j][r]);
      }
  __syncthreads();
  copy_out128(smem, ykv16 + ((size_t)z * TT + t0) * DD + d0, DD, tid);
}

// ---------------------------------------------------------------------------
// K3: per-row mean/rstd of group-local ykv16 (bf16 rows of 768). 1 wave/row.
// ---------------------------------------------------------------------------
__global__ __launch_bounds__(256) void k3_stats(
    const u16* __restrict__ ykv16, float* __restrict__ mu, float* __restrict__ rs) {
  const int row = blockIdx.x * 4 + (threadIdx.x >> 6);
  const int lane = threadIdx.x & 63;
  const u16* p = ykv16 + (size_t)row * DD;
  float sum = 0.f, sq = 0.f;
#pragma unroll
  for (int i = 0; i < 3; ++i) {
    ushort4 v = *(const ushort4*)&p[(lane << 2) + i * 256];
    float f0 = b2f(v.x), f1 = b2f(v.y), f2 = b2f(v.z), f3 = b2f(v.w);
    sum += f0 + f1 + f2 + f3;
    sq += f0 * f0 + f1 * f1 + f2 * f2 + f3 * f3;
  }
#pragma unroll
  for (int off = 32; off; off >>= 1) {
    sum += __shfl_xor(sum, off);
    sq += __shfl_xor(sq, off);
  }
  if (lane == 0) {
    float m = sum * (1.f / 768.f);
    float v = sq * (1.f / 768.f) - m * m;
    mu[row] = m;
    rs[row] = rsqrtf(v + 1e-5f);
  }
}

// ---------------------------------------------------------------------------
// K4: raw GEMM ykv16 @ ENCVT[h]^T with LN as epilogue affine; xs via inverse
// rope of QR16 (CS table); out2 = xs*ys (fp32); XY (bf16) written IN PLACE
// into QR16's storage.  Single-pass full-tile epilogue.
// ---------------------------------------------------------------------------
__global__ __launch_bounds__(256) void k4_xy(
    const u16* __restrict__ ykv16, const u16* __restrict__ encvt,
    const float2* __restrict__ CS,
    u16* __restrict__ qrxy, const float* __restrict__ mu,
    const float* __restrict__ rs, const float* __restrict__ colsum,
    float* __restrict__ out2, int bh0) {
  const int z = blockIdx.z;
  const int bh = bh0 + z, h = bh % NHH;
  const int t0 = blockIdx.x * 128, n0 = blockIdx.y * 128;
  GEMM_PROLOGUE();
  PIPELINED_K_LOOP(ykv16 + ((size_t)z * TT + t0) * DD, DD,
                   encvt + ((size_t)h * NN + n0) * DD, DD, DD);
  __syncthreads();
#pragma unroll
  for (int i = 0; i < 4; ++i) {
    float muv[4], rsv[4];
#pragma unroll
    for (int r = 0; r < 4; ++r) {
      const int lrow = z * TT + t0 + wr * 64 + i * 16 + quad * 4 + r;
      muv[r] = mu[lrow];
      rsv[r] = rs[lrow];
    }
#pragma unroll
    for (int j = 0; j < 4; ++j) {
      const int n = n0 + wc * 64 + j * 16 + col16;
      const float csum = colsum[h * NN + n];
#pragma unroll
      for (int r = 0; r < 4; ++r) {
        const int lrow = wr * 64 + i * 16 + quad * 4 + r;
        const int t = t0 + lrow;
        const float ys = fmaxf(rsv[r] * acc[i][j][r] - rsv[r] * muv[r] * csum, 0.f);
        const size_t gi = ((size_t)bh * TT + t) * NN + n;
        const unsigned pq = *(const unsigned*)&qrxy[gi & ~(size_t)1];
        const float lo = b2f((u16)pq), hi = b2f((u16)(pq >> 16));
        const float2 cs = CS[t * 128 + (n >> 1)];
        const float xs = (n & 1) ? (hi * cs.x - lo * cs.y)
                                 : (lo * cs.x + hi * cs.y);
        const float val = ys * xs;
        out2[gi] = val;
        smem[lrow * 128 + wc * 64 + j * 16 + col16] = f2b(val);
      }
    }
  }
  __syncthreads();
  copy_out128(smem, qrxy + ((size_t)bh * TT + t0) * NN + n0, NN, tid);
}

// ---------------------------------------------------------------------------
// K5: ymlp = flat(XY) @ DECT^T.  M=4096, N=768, K=3072.  64x64 tiles,
// BK=64 (two 32-panels per barrier-pair), dbuf + vmcnt(4).
// ---------------------------------------------------------------------------
__global__ __launch_bounds__(256) void k5_mlp(
    const u16* __restrict__ xyq, const u16* __restrict__ dect,
    float* __restrict__ ymlp) {
  __shared__ __attribute__((aligned(16))) u16 sm[16384];
  u16* buf0 = sm;            // A0 +0, A1 +2048, B0 +4096, B1 +6144
  u16* buf1 = sm + 8192;
  const int tid = threadIdx.x;
  const int w = tid >> 6, lane = tid & 63;
  const int wr = w >> 1, wc = w & 1;
  const int m16 = lane & 15, quad = lane >> 4;
  const int m0 = blockIdx.x * 64, d0 = blockIdx.y * 64;
  f32x4 acc[2][2];
#pragma unroll
  for (int i = 0; i < 2; ++i)
#pragma unroll
    for (int j = 0; j < 2; ++j) acc[i][j] = (f32x4){0.f, 0.f, 0.f, 0.f};
  const int ar = w * 16 + (lane >> 2);      // A row within 64-tile
  const int m = m0 + ar;
  const int b = m >> 11, t = m & (TT - 1);
  const int kc = (lane & 3) << 3;
#define K5_STAGE(buf, k0)                                                   \
  {                                                                         \
    const int hh_ = (k0) >> 8;                                              \
    const int kk_ = ((k0) & 255) + kc;                                      \
    const u16* ap_ = xyq + ((size_t)(b * NHH + hh_) * TT + t) * NN;         \
    async16(ap_ + kk_, (buf) + w * 512);                                    \
    async16(ap_ + kk_ + 32, (buf) + 2048 + w * 512);                        \
    stage64x32(dect + (size_t)d0 * (NHH * NN) + (k0), NHH * NN,             \
               (buf) + 4096, tid);                                          \
    stage64x32(dect + (size_t)d0 * (NHH * NN) + (k0) + 32, NHH * NN,        \
               (buf) + 6144, tid);                                          \
  }
  const int NK = (NHH * NN) / 64;           // 48 steps
  K5_STAGE(buf0, 0);
  for (int s = 0; s < NK; ++s) {
    u16* cb = (s & 1) ? buf1 : buf0;
    u16* nb = (s & 1) ? buf0 : buf1;
    if (s + 1 < NK) {
      K5_STAGE(nb, (s + 1) * 64);
      asm volatile("s_waitcnt vmcnt(4)" ::: "memory");
    } else {
      asm volatile("s_waitcnt vmcnt(0)" ::: "memory");
    }
    __builtin_amdgcn_s_barrier();
    __builtin_amdgcn_sched_barrier(0);
#pragma unroll
    for (int half = 0; half < 2; ++half) {
      bf16x8 a[2], bb[2];
#pragma unroll
      for (int i = 0; i < 2; ++i)
        a[i] = *(const bf16x8*)&cb[half * 2048 + (wr * 32 + i * 16 + m16) * 32 + quad * 8];
#pragma unroll
      for (int j = 0; j < 2; ++j)
        bb[j] = *(const bf16x8*)&cb[4096 + half * 2048 + (wc * 32 + j * 16 + m16) * 32 + quad * 8];
#pragma unroll
      for (int i = 0; i < 2; ++i)
#pragma unroll
        for (int j = 0; j < 2; ++j)
          acc[i][j] = __builtin_amdgcn_mfma_f32_16x16x32_bf16(a[i], bb[j], acc[i][j], 0, 0, 0);
    }
    __builtin_amdgcn_sched_barrier(0);
    __builtin_amdgcn_s_barrier();
  }
#undef K5_STAGE
#pragma unroll
  for (int i = 0; i < 2; ++i)
#pragma unroll
    for (int j = 0; j < 2; ++j) {
      const int d = d0 + wc * 32 + j * 16 + m16;
#pragma unroll
      for (int r = 0; r < 4; ++r) {
        const int mm = m0 + wr * 32 + i * 16 + quad * 4 + r;
        ymlp[(size_t)mm * DD + d] = acc[i][j][r];
      }
    }
}

// ---------------------------------------------------------------------------
// K6: y = ln(ymlp)*sqrt(0.1/(ra+1e-6))*scale; out1 = ln(x+y). Block per row.
// ---------------------------------------------------------------------------
__global__ __launch_bounds__(256) void k6_final(
    const float* __restrict__ ymlp, const float* __restrict__ x,
    const float* __restrict__ scale, const float* __restrict__ ra,
    float* __restrict__ out1) {
  const int row = blockIdx.x;
  const int tid = threadIdx.x;
  const int wid = tid >> 6, lane = tid & 63;
  __shared__ float red[8];
  float v[3];
  float sum = 0.f, sq = 0.f;
#pragma unroll
  for (int j = 0; j < 3; ++j) {
    v[j] = ymlp[(size_t)row * DD + tid + j * 256];
    sum += v[j]; sq += v[j] * v[j];
  }
#pragma unroll
  for (int off = 32; off; off >>= 1) { sum += __shfl_xor(sum, off); sq += __shfl_xor(sq, off); }
  if (lane == 0) { red[wid] = sum; red[4 + wid] = sq; }
  __syncthreads();
  sum = red[0] + red[1] + red[2] + red[3];
  sq = red[4] + red[5] + red[6] + red[7];
  const float m1 = sum * (1.f / 768.f);
  const float r1 = rsqrtf(sq * (1.f / 768.f) - m1 * m1 + 1e-5f);
  float z[3];
  float sum2 = 0.f, sq2 = 0.f;
#pragma unroll
  for (int j = 0; j < 3; ++j) {
    const int d = tid + j * 256;
    float y = (v[j] - m1) * r1 * sqrtf(0.1f / (ra[d] + 1e-6f)) * scale[d];
    z[j] = x[(size_t)row * DD + d] + y;
    sum2 += z[j]; sq2 += z[j] * z[j];
  }
  __syncthreads();
#pragma unroll
  for (int off = 32; off; off >>= 1) { sum2 += __shfl_xor(sum2, off); sq2 += __shfl_xor(sq2, off); }
  if (lane == 0) { red[wid] = sum2; red[4 + wid] = sq2; }
  __syncthreads();
  sum2 = red[0] + red[1] + red[2] + red[3];
  sq2 = red[4] + red[5] + red[6] + red[7];
  const float m2 = sum2 * (1.f / 768.f);
  const float r2 = rsqrtf(sq2 * (1.f / 768.f) - m2 * m2 + 1e-5f);
#pragma unroll
  for (int j = 0; j < 3; ++j)
    out1[(size_t)row * DD + tid + j * 256] = (z[j] - m2) * r2;
}

// ---------------------------------------------------------------------------
extern "C" void kernel_launch(void* const* d_in, const int* in_sizes, int n_in,
                              void* d_out, int out_size, void* d_ws, size_t ws_size,
                              hipStream_t stream) {
  const float* x = (const float*)d_in[0];
  const float* enc = (const float*)d_in[1];
  const float* encv = (const float*)d_in[2];
  const float* dec = (const float*)d_in[3];
  const float* scale = (const float*)d_in[4];
  const float* ra = (const float*)d_in[5];
  float* out1 = (float*)d_out;
  float* out2 = out1 + (size_t)BB * TT * DD;
  float* ymlp = out1;                         // k5 scratch, k6 in-place

  const int NS = BB * NHH;  // 24 slices
  unsigned char* p = (unsigned char*)d_ws;
  u16* X16 = (u16*)p;    p += (size_t)BB * TT * DD * 2;
  u16* XT16 = (u16*)p;   p += (size_t)BB * DD * TT * 2;
  u16* ENCT = (u16*)p;   p += (size_t)NHH * NN * DD * 2;
  u16* ENCVT = (u16*)p;  p += (size_t)NHH * NN * DD * 2;
  u16* DECT = (u16*)p;   p += (size_t)DD * NHH * NN * 2;
  u16* QR16 = (u16*)p;   p += (size_t)NS * TT * NN * 2;   // holds QR, then XY
  u16* QRT16 = (u16*)p;  p += (size_t)NS * NN * TT * 2;
  float* COLSUM = (float*)p; p += (size_t)NHH * NN * 4;
  float2* CS = (float2*)p;   p += (size_t)TT * (NN / 2) * sizeof(float2);
  // Adaptive, BALANCED per-slice attention pool.
  const size_t SLICE_B = (size_t)TT * CH * 2 + 3 * (size_t)DD * NN * 2 +
                         (size_t)TT * DD * 2 + (size_t)TT * 8;
  size_t fixed = (size_t)(p - (unsigned char*)d_ws);
  size_t rem = (ws_size > fixed) ? ws_size - fixed : 0;
  int GSmax = (int)(rem / SLICE_B);
  if (GSmax < 1) GSmax = 1;
  if (GSmax > NS) GSmax = NS;
  const int ngrp = (NS + GSmax - 1) / GSmax;
  const int GS = (NS + ngrp - 1) / ngrp;     // balanced groups
  u16* SB = (u16*)p;     p += (size_t)GS * TT * CH * 2;
  u16* H16 = (u16*)p;    p += (size_t)GS * 3 * DD * NN * 2;
  u16* YKV16 = (u16*)p;  p += (size_t)GS * TT * DD * 2;
  float* MU = (float*)p; p += (size_t)GS * TT * 4;
  float* RS = (float*)p; p += (size_t)GS * TT * 4;

  // One-time conversions / transposes
  cvt_bf16<<<dim3((BB * TT * DD) / 1024), 256, 0, stream>>>(x, X16, (size_t)BB * TT * DD / 4);
  tcvt_bf16<<<dim3(DD / 32, TT / 32, BB), 256, 0, stream>>>(
      x, XT16, TT, DD, (size_t)TT * DD, (size_t)DD * TT);
  tcvt_bf16<<<dim3(NN / 32, DD / 32, NHH), 256, 0, stream>>>(
      enc, ENCT, DD, NN, (size_t)DD * NN, (size_t)NN * DD);
  tcvt_bf16<<<dim3(NN / 32, DD / 32, NHH), 256, 0, stream>>>(
      encv, ENCVT, DD, NN, (size_t)DD * NN, (size_t)NN * DD);
  tcvt_bf16<<<dim3(DD / 32, (NHH * NN) / 32, 1), 256, 0, stream>>>(
      dec, DECT, NHH * NN, DD, 0, 0);
  k_colsum<<<dim3(NHH * NN / 4), 256, 0, stream>>>(ENCVT, COLSUM);
  k_cstab<<<dim3(TT * (NN / 2) / 256), 256, 0, stream>>>(CS);

  k1_encode<<<dim3(BB * TT / 128, NN / 128, NHH), 256, 0, stream>>>(
      X16, ENCT, CS, QR16, QRT16);

  for (int bh0 = 0; bh0 < NS; bh0 += GS) {
    const int gs = imin(GS, NS - bh0);
    kS_band<<<dim3(40, gs), 256, 0, stream>>>(QR16, SB, bh0);
    kB_all<<<dim3(DD / 64, NN / 128, gs), 256, 0, stream>>>(
        XT16, QRT16, H16, bh0);
    kA_attn<<<dim3(96 * gs), 256, 0, stream>>>(
        QR16, H16, SB, XT16, YKV16, bh0);
    k3_stats<<<dim3(gs * TT / 4), 256, 0, stream>>>(YKV16, MU, RS);
    k4_xy<<<dim3(TT / 128, NN / 128, gs), 256, 0, stream>>>(
        YKV16, ENCVT, CS, QR16, MU, RS, COLSUM, out2, bh0);
  }

  k5_mlp<<<dim3(BB * TT / 64, DD / 64), 256, 0, stream>>>(QR16, DECT, ymlp);
  k6_final<<<dim3(BB * TT), 256, 0, stream>>>(ymlp, x, scale, ra, out1);
}

// Round 4
// 379.851 us; speedup vs baseline: 1.2813x; 1.0591x over previous
//
#include <hip/hip_runtime.h>
#include <math.h>

#define TT 2048
#define DD 768
#define NN 256
#define NHH 12
#define BB 2
#define CH 512           // attention chunk (4 chunks of 4 x 128-tiles)

typedef unsigned short u16;
typedef __attribute__((ext_vector_type(8))) short bf16x8;
typedef __attribute__((ext_vector_type(8))) unsigned short u16x8;
typedef __attribute__((ext_vector_type(4))) float f32x4;

static inline int imin(int a, int b) { return a < b ? a : b; }

__device__ __forceinline__ u16 f2b(float f) {
  union { float f; unsigned u; } a; a.f = f;
  unsigned r = a.u + 0x7FFF + ((a.u >> 16) & 1);
  return (u16)(r >> 16);
}
__device__ __forceinline__ float b2f(u16 h) {
  union { unsigned u; float f; } a; a.u = ((unsigned)h) << 16;
  return a.f;
}

__device__ __forceinline__ void async16(const void* g, void* l) {
  __builtin_amdgcn_global_load_lds(
      (const __attribute__((address_space(1))) unsigned*)g,
      (__attribute__((address_space(3))) unsigned*)l, 16, 0, 0);
}

// Stage a 128x32 bf16 tile (row-major, ld in elements) into LDS [128][32].
__device__ __forceinline__ void stage128x32(
    const u16* __restrict__ gbase, size_t ld, u16* lds, int tid) {
  const int w = tid >> 6, l = tid & 63;
  const int r = l >> 2, kc = (l & 3) << 3;
#pragma unroll
  for (int q = 0; q < 2; ++q) {
    const int row0 = w * 32 + q * 16;
    async16(gbase + (size_t)(row0 + r) * ld + kc, lds + row0 * 32);
  }
}

// Stage a 64x32 bf16 tile into LDS [64][32]. One async16 per thread.
__device__ __forceinline__ void stage64x32(
    const u16* __restrict__ gbase, size_t ld, u16* lds, int tid) {
  const int w = tid >> 6, l = tid & 63;
  const int r = w * 16 + (l >> 2), kc = (l & 3) << 3;
  async16(gbase + (size_t)r * ld + kc, lds + w * 512);
}

// 16 MFMAs of one BK=32 step; wave (wr,wc) computes 64x64 of the 128x128 tile.
__device__ __forceinline__ void mfma_step(
    const u16* As, const u16* Bs, int wr, int wc, int lane, f32x4 acc[4][4]) {
  const int m16 = lane & 15, quad = lane >> 4;
  bf16x8 a[4], b[4];
#pragma unroll
  for (int i = 0; i < 4; ++i)
    a[i] = *(const bf16x8*)&As[(wr * 64 + i * 16 + m16) * 32 + quad * 8];
#pragma unroll
  for (int j = 0; j < 4; ++j)
    b[j] = *(const bf16x8*)&Bs[(wc * 64 + j * 16 + m16) * 32 + quad * 8];
#pragma unroll
  for (int i = 0; i < 4; ++i)
#pragma unroll
    for (int j = 0; j < 4; ++j)
      acc[i][j] = __builtin_amdgcn_mfma_f32_16x16x32_bf16(a[i], b[j], acc[i][j], 0, 0, 0);
}

// copy a full 128x128 u16 tile from LDS (row-major) to global rows of ld.
__device__ __forceinline__ void copy_out128(
    const u16* buf, u16* g, size_t ld, int tid) {
#pragma unroll
  for (int s = 0; s < 8; ++s) {
    const int off = (s * 256 + tid) * 8;
    const int row = off >> 7, col = off & 127;
    *(u16x8*)&g[(size_t)row * ld + col] = *(const u16x8*)&buf[off];
  }
}

#define GEMM_PROLOGUE()                                            \
  __shared__ __attribute__((aligned(16))) u16 smem[32768];         \
  const int tid = threadIdx.x;                                     \
  const int w = tid >> 6, lane = tid & 63;                         \
  const int wr = w >> 1, wc = w & 1;                               \
  const int col16 = lane & 15, quad = lane >> 4;                   \
  f32x4 acc[4][4];                                                 \
  _Pragma("unroll") for (int i = 0; i < 4; ++i)                    \
  _Pragma("unroll") for (int j = 0; j < 4; ++j)                    \
      acc[i][j] = (f32x4){0.f, 0.f, 0.f, 0.f};

// Double-buffered, counted-vmcnt pipelined K loop, BK=64 (kA's proven
// structure): 32 MFMA per barrier-pair, 8 async16/thread/phase, vmcnt(8)
// keeps the next panel's loads in flight across the raw barrier.
#define PIPELINED_K_LOOP64(ABASE, ALD, BBASE, BLD, KTOT)                    \
  {                                                                         \
    stage128x32((ABASE), (ALD), smem, tid);                                 \
    stage128x32((ABASE) + 32, (ALD), smem + 4096, tid);                     \
    stage128x32((BBASE), (BLD), smem + 8192, tid);                          \
    stage128x32((BBASE) + 32, (BLD), smem + 12288, tid);                    \
    const int np_ = (KTOT) / 64;                                            \
    for (int pp_ = 0; pp_ < np_; ++pp_) {                                   \
      u16* cb_ = (pp_ & 1) ? smem + 16384 : smem;                           \
      u16* nb_ = (pp_ & 1) ? smem : smem + 16384;                           \
      if (pp_ + 1 < np_) {                                                  \
        const int kn_ = (pp_ + 1) * 64;                                     \
        stage128x32((ABASE) + kn_, (ALD), nb_, tid);                        \
        stage128x32((ABASE) + kn_ + 32, (ALD), nb_ + 4096, tid);            \
        stage128x32((BBASE) + kn_, (BLD), nb_ + 8192, tid);                 \
        stage128x32((BBASE) + kn_ + 32, (BLD), nb_ + 12288, tid);           \
        asm volatile("s_waitcnt vmcnt(8)" ::: "memory");                    \
      } else {                                                              \
        asm volatile("s_waitcnt vmcnt(0)" ::: "memory");                    \
      }                                                                     \
      __builtin_amdgcn_s_barrier();                                         \
      __builtin_amdgcn_sched_barrier(0);                                    \
      mfma_step(cb_, cb_ + 8192, wr, wc, lane, acc);                        \
      mfma_step(cb_ + 4096, cb_ + 12288, wr, wc, lane, acc);                \
      __builtin_amdgcn_sched_barrier(0);                                    \
      __builtin_amdgcn_s_barrier();                                         \
    }                                                                       \
  }

// ---------------------------------------------------------------------------
__global__ __launch_bounds__(256) void cvt_bf16(
    const float* __restrict__ in, u16* __restrict__ out, size_t n4) {
  size_t i = ((size_t)blockIdx.x * 256 + threadIdx.x) * 4;
  if (i >= n4 * 4) return;
  float4 v = *(const float4*)&in[i];
  u16 o[4] = {f2b(v.x), f2b(v.y), f2b(v.z), f2b(v.w)};
  *(ushort4*)&out[i] = *(ushort4*)o;
}

__global__ __launch_bounds__(256) void tcvt_bf16(
    const float* __restrict__ in, u16* __restrict__ out, int R, int C,
    size_t inStride, size_t outStride) {
  __shared__ float tile[32][33];
  const float* ip = in + (size_t)blockIdx.z * inStride;
  u16* op = out + (size_t)blockIdx.z * outStride;
  const int c0 = blockIdx.x * 32, r0 = blockIdx.y * 32;
  const int tx = threadIdx.x & 31, ty = threadIdx.x >> 5;
#pragma unroll
  for (int p = 0; p < 4; ++p)
    tile[ty + p * 8][tx] = ip[(size_t)(r0 + ty + p * 8) * C + c0 + tx];
  __syncthreads();
#pragma unroll
  for (int p = 0; p < 4; ++p)
    op[(size_t)(c0 + ty + p * 8) * R + r0 + tx] = f2b(tile[tx][ty + p * 8]);
}

__global__ __launch_bounds__(256) void k_colsum(
    const u16* __restrict__ encvt, float* __restrict__ colsum) {
  const int row = blockIdx.x * 4 + (threadIdx.x >> 6);
  const int lane = threadIdx.x & 63;
  const u16* pr = encvt + (size_t)row * DD;
  float s = 0.f;
#pragma unroll
  for (int i = 0; i < 3; ++i) {
    ushort4 v = *(const ushort4*)&pr[(lane << 2) + i * 256];
    s += b2f(v.x) + b2f(v.y) + b2f(v.z) + b2f(v.w);
  }
#pragma unroll
  for (int off = 32; off; off >>= 1) s += __shfl_xor(s, off);
  if (lane == 0) colsum[row] = s;
}

// Precompute rope cos/sin table (bit-identical to the inline math).
__global__ __launch_bounds__(256) void k_cstab(float2* __restrict__ cs) {
  const int idx = blockIdx.x * 256 + threadIdx.x;   // t*128 + n2
  const int t = idx >> 7, n2 = idx & 127;
  const float freq = exp2f((float)(2 * n2) * -0.0625f) * 0.15915494309189535f;
  const float phase = (float)t * freq;
  const float ph = (phase - floorf(phase)) * 6.283185307179586f;
  cs[idx] = make_float2(__cosf(ph), __sinf(ph));
}

// ---------------------------------------------------------------------------
// K1: latent = X16 @ ENCT[h]^T; relu; rope -> QR16 [b][h][t][n] AND
// QRT16 [b][h][n][t].  BK=64 pipeline; XOR-swizzled epilogue tile so the
// QRT column read is bank-conflict-free (swz varies per 8-row group, which
// is the per-lane row granularity of the transpose read).
// ---------------------------------------------------------------------------
__device__ __forceinline__ int swz8(int row) { return ((row >> 3) & 7) << 3; }

__global__ __launch_bounds__(256) void k1_encode(
    const u16* __restrict__ x16, const u16* __restrict__ enct,
    const float2* __restrict__ CS,
    u16* __restrict__ qr16, u16* __restrict__ qrt16) {
  const int h = blockIdx.z;
  const int m0 = blockIdx.x * 128, n0 = blockIdx.y * 128;
  GEMM_PROLOGUE();
  PIPELINED_K_LOOP64(x16 + (size_t)m0 * DD, DD,
                     enct + ((size_t)h * NN + n0) * DD, DD, DD);
  __syncthreads();
#pragma unroll
  for (int i = 0; i < 4; ++i)
#pragma unroll
    for (int j = 0; j < 4; ++j) {
      const int n = n0 + wc * 64 + j * 16 + col16;
      float rv[4], pv[4];
#pragma unroll
      for (int r = 0; r < 4; ++r) rv[r] = fmaxf(acc[i][j][r], 0.f);
#pragma unroll
      for (int r = 0; r < 4; ++r) pv[r] = __shfl_xor(rv[r], 1);
#pragma unroll
      for (int r = 0; r < 4; ++r) {
        const int lrow = wr * 64 + i * 16 + quad * 4 + r;
        const int t = (m0 + lrow) & (TT - 1);
        const float2 cs = CS[t * 128 + (n >> 1)];
        const float o = (n & 1) ? (rv[r] * cs.x + pv[r] * cs.y)
                                : (rv[r] * cs.x - pv[r] * cs.y);
        smem[lrow * 128 + ((wc * 64 + j * 16 + col16) ^ swz8(lrow))] = f2b(o);
      }
    }
  __syncthreads();
  const int bq = m0 >> 11, tb = m0 & (TT - 1);
  const size_t sl = (size_t)(bq * NHH + h);
  // row-major copy (swizzle-aware source)
  u16* qg = qr16 + (sl * TT + tb) * NN + n0;
#pragma unroll
  for (int s = 0; s < 8; ++s) {
    const int off = (s * 256 + tid) * 8;
    const int row = off >> 7, col = off & 127;
    *(u16x8*)&qg[(size_t)row * NN + col] =
        *(const u16x8*)&smem[row * 128 + (col ^ swz8(row))];
  }
  // transposed copy: QRT16[sl][n][t] = tile[t][n]; swz varies per lane now.
#pragma unroll
  for (int s = 0; s < 8; ++s) {
    const int off = (s * 256 + tid) * 8;
    const int nr = off >> 7, tc = off & 127;
    const int sw = swz8(tc);                 // tc 8-aligned: same for tc..tc+7
    u16 vals[8];
#pragma unroll
    for (int k = 0; k < 8; ++k) vals[k] = smem[(tc + k) * 128 + (nr ^ sw)];
    *(u16x8*)&qrt16[(sl * NN + n0 + nr) * TT + tb + tc] = *(u16x8*)vals;
  }
}

// ---------------------------------------------------------------------------
// kS: block-diagonal band of S = QR QR^T (strict lower), 40 tiles/slice.
// ---------------------------------------------------------------------------
__global__ __launch_bounds__(256) void kS_band(
    const u16* __restrict__ qr16, u16* __restrict__ sb, int bh0) {
  const int z = blockIdx.y;                  // group-local slice
  const int bh = bh0 + z;
  const int cc = blockIdx.x / 10, rr = blockIdx.x % 10;
  int i = (int)((sqrtf(8.f * rr + 1.f) - 1.f) * 0.5f);
  while ((i + 1) * (i + 2) / 2 <= rr) ++i;
  while (i * (i + 1) / 2 > rr) --i;
  const int j = rr - i * (i + 1) / 2;
  const int t0 = (cc * 4 + i) * 128;
  const int s0 = cc * CH + j * 128;
  const u16* q = qr16 + (size_t)bh * TT * NN;
  GEMM_PROLOGUE();
  PIPELINED_K_LOOP64(q + (size_t)t0 * NN, NN, q + (size_t)s0 * NN, NN, NN);
  const bool diag = (i == j);
  __syncthreads();
#pragma unroll
  for (int ii = 0; ii < 4; ++ii)
#pragma unroll
    for (int jj = 0; jj < 4; ++jj) {
      const int s = s0 + wc * 64 + jj * 16 + col16;
#pragma unroll
      for (int r = 0; r < 4; ++r) {
        const int lrow = wr * 64 + ii * 16 + quad * 4 + r;
        const int t = t0 + lrow;
        float v = acc[ii][jj][r];
        if (diag && s >= t) v = 0.f;
        smem[lrow * 128 + wc * 64 + jj * 16 + col16] = f2b(v);
      }
    }
  __syncthreads();
  copy_out128(smem, sb + ((size_t)z * TT + t0) * CH + j * 128, CH, tid);
}

// ---------------------------------------------------------------------------
// kB_all: each block owns a 64(d) x 128(n) tile of H, K=0..1536 fp32 acc,
// bf16 snapshot H16[z][c] at each chunk boundary.  BK=64 phases (24 total),
// 6 async16/thread/phase -> vmcnt(6).  LDS: 2x24KB dbuf + 16KB snapshot.
// ---------------------------------------------------------------------------
__global__ __launch_bounds__(256) void kB_all(
    const u16* __restrict__ xt16, const u16* __restrict__ qrt16,
    u16* __restrict__ h16, int bh0) {
  __shared__ __attribute__((aligned(16))) u16 sm[32768];
  u16* buf0 = sm;            // A0 +0, A1 +2048, B0 +4096, B1 +8192 (u16)
  u16* buf1 = sm + 12288;
  u16* snap = sm + 24576;    // 64x128 u16
  const int tid = threadIdx.x;
  const int w = tid >> 6, lane = tid & 63;
  const int m16 = lane & 15, quad = lane >> 4;
  const int z = blockIdx.z;
  const int bh = bh0 + z, b = bh / NHH;
  const int d0 = blockIdx.x * 64, n0 = blockIdx.y * 128;
  f32x4 acc[4][2];
#pragma unroll
  for (int i = 0; i < 4; ++i)
#pragma unroll
    for (int j = 0; j < 2; ++j) acc[i][j] = (f32x4){0.f, 0.f, 0.f, 0.f};
  const u16* Ab = xt16 + ((size_t)b * DD + d0) * TT;
  const u16* Bb = qrt16 + ((size_t)bh * NN + n0) * TT;
#define KB_STAGE(buf, k0)                                                   \
  {                                                                         \
    stage64x32(Ab + (k0), TT, (buf), tid);                                  \
    stage64x32(Ab + (k0) + 32, TT, (buf) + 2048, tid);                      \
    stage128x32(Bb + (k0), TT, (buf) + 4096, tid);                          \
    stage128x32(Bb + (k0) + 32, TT, (buf) + 8192, tid);                     \
  }
  for (int c = 0; c < 3; ++c) {
    const int kbase = c * CH;
    KB_STAGE(buf0, kbase);
    for (int s = 0; s < CH / 64; ++s) {
      u16* cb = (s & 1) ? buf1 : buf0;
      u16* nb = (s & 1) ? buf0 : buf1;
      if (s + 1 < CH / 64) {
        KB_STAGE(nb, kbase + (s + 1) * 64);
        asm volatile("s_waitcnt vmcnt(6)" ::: "memory");
      } else {
        asm volatile("s_waitcnt vmcnt(0)" ::: "memory");
      }
      __builtin_amdgcn_s_barrier();
      __builtin_amdgcn_sched_barrier(0);
#pragma unroll
      for (int half = 0; half < 2; ++half) {
        bf16x8 a[4], bb[2];
#pragma unroll
        for (int i = 0; i < 4; ++i)
          a[i] = *(const bf16x8*)&cb[half * 2048 + (i * 16 + m16) * 32 + quad * 8];
#pragma unroll
        for (int j = 0; j < 2; ++j)
          bb[j] = *(const bf16x8*)&cb[4096 + half * 4096 +
                                      (w * 32 + j * 16 + m16) * 32 + quad * 8];
#pragma unroll
        for (int i = 0; i < 4; ++i)
#pragma unroll
          for (int j = 0; j < 2; ++j)
            acc[i][j] = __builtin_amdgcn_mfma_f32_16x16x32_bf16(a[i], bb[j], acc[i][j], 0, 0, 0);
      }
      __builtin_amdgcn_sched_barrier(0);
      __builtin_amdgcn_s_barrier();
    }
    // snapshot H16[z][c]
#pragma unroll
    for (int i = 0; i < 4; ++i)
#pragma unroll
      for (int j = 0; j < 2; ++j)
#pragma unroll
        for (int r = 0; r < 4; ++r)
          snap[(i * 16 + quad * 4 + r) * 128 + w * 32 + j * 16 + m16] =
              f2b(acc[i][j][r]);
    __syncthreads();
    u16* hd = h16 + (size_t)(z * 3 + c) * DD * NN;
#pragma unroll
    for (int s4 = 0; s4 < 4; ++s4) {
      const int off = (s4 * 256 + tid) * 8;
      const int row = off >> 7, col = off & 127;
      *(u16x8*)&hd[(size_t)(d0 + row) * NN + n0 + col] = *(const u16x8*)&snap[off];
    }
    __syncthreads();
  }
#undef KB_STAGE
}

// ---------------------------------------------------------------------------
// kA: 128x128 output, unified panel-pipelined K sequence.
// 1D grid, bijective chunked XCD swizzle (T1) + LPT tt order.
// ---------------------------------------------------------------------------
__device__ static const int TTORD[16] = {15, 11, 7, 14, 10, 6, 13, 9,
                                         5, 3, 12, 8, 4, 2, 1, 0};

__global__ __launch_bounds__(256) void kA_attn(
    const u16* __restrict__ qr16, const u16* __restrict__ h16,
    const u16* __restrict__ sb, const u16* __restrict__ xt16,
    u16* __restrict__ ykv16, int bh0) {
  __shared__ __attribute__((aligned(16))) u16 smem[32768];  // 2 x 32KB buffers
  const int tid = threadIdx.x;
  const int w = tid >> 6, lane = tid & 63;
  const int wr = w >> 1, wc = w & 1;
  const int col16 = lane & 15, quad = lane >> 4;
  const int nwg = gridDim.x;
  const int bid = blockIdx.x;
  const int qq = nwg >> 3, r8 = nwg & 7;
  const int xcd = bid & 7, pos = bid >> 3;
  const int wg = (xcd < r8 ? xcd * (qq + 1) : r8 * (qq + 1) + (xcd - r8) * qq) + pos;
  const int z = wg / 96;
  const int tt = TTORD[(wg / 6) & 15];       // LPT within chunk
  const int d0 = (wg % 6) * 128;
  const int bh = bh0 + z, b = bh / NHH;
  const int c = tt >> 2, it = tt & 3;
  const int t0 = tt * 128;
  f32x4 acc[4][4];
#pragma unroll
  for (int i = 0; i < 4; ++i)
#pragma unroll
    for (int j = 0; j < 4; ++j) acc[i][j] = (f32x4){0.f, 0.f, 0.f, 0.f};

  const int c4 = (c > 0) ? 4 : 0;
  const int nP = c4 + (it + 1) * 2;          // BK=64 panels total
  const u16* hs = h16 + ((size_t)(z * 3 + (c > 0 ? c - 1 : 0)) * DD + d0) * NN;
  const u16* qb = qr16 + ((size_t)bh * TT + t0) * NN;
  const u16* sbb = sb + ((size_t)z * TT + t0) * CH;
  const u16* xb = xt16 + ((size_t)b * DD + d0) * TT + c * CH;

#define KA_STAGE(buf, p)                                                  \
  {                                                                       \
    const u16 *pa_, *pb_; size_t la_, lb_;                                \
    if ((p) < c4) {                                                       \
      pa_ = qb + (p) * 64; la_ = NN;                                      \
      pb_ = hs + (p) * 64; lb_ = NN;                                      \
    } else {                                                              \
      const int q_ = (p) - c4;                                            \
      const int j_ = q_ >> 1, kk_ = (q_ & 1) << 6;                        \
      pa_ = sbb + j_ * 128 + kk_; la_ = CH;                               \
      pb_ = xb + j_ * 128 + kk_; lb_ = TT;                                \
    }                                                                     \
    stage128x32(pa_, la_, (buf), tid);                                    \
    stage128x32(pa_ + 32, la_, (buf) + 4096, tid);                        \
    stage128x32(pb_, lb_, (buf) + 8192, tid);                             \
    stage128x32(pb_ + 32, lb_, (buf) + 12288, tid);                       \
  }

  u16* bufA = smem;
  u16* bufB = smem + 16384;
  KA_STAGE(bufA, 0);
  for (int p = 0; p < nP; ++p) {
    u16* cb = (p & 1) ? bufB : bufA;
    u16* nb = (p & 1) ? bufA : bufB;
    if (p + 1 < nP) {
      KA_STAGE(nb, p + 1);
      asm volatile("s_waitcnt vmcnt(8)" ::: "memory");
    } else {
      asm volatile("s_waitcnt vmcnt(0)" ::: "memory");
    }
    __builtin_amdgcn_s_barrier();            // publish panel p across waves
    __builtin_amdgcn_sched_barrier(0);
    mfma_step(cb, cb + 8192, wr, wc, lane, acc);
    mfma_step(cb + 4096, cb + 12288, wr, wc, lane, acc);
    __builtin_amdgcn_sched_barrier(0);
    __builtin_amdgcn_s_barrier();            // reads of cb done before overwrite
  }
#undef KA_STAGE

  __syncthreads();
#pragma unroll
  for (int i = 0; i < 4; ++i)
#pragma unroll
    for (int j = 0; j < 4; ++j)
#pragma unroll
      for (int r = 0; r < 4; ++r) {
        const int lrow = wr * 64 + i * 16 + quad * 4 + r;
        smem[lrow * 128 + wc * 64 + j * 16 + col16] = f2b(acc[i][j][r]);
      }
  __syncthreads();
  copy_out128(smem, ykv16 + ((size_t)z * TT + t0) * DD + d0, DD, tid);
}

// ---------------------------------------------------------------------------
// K3: per-row mean/rstd of group-local ykv16 (bf16 rows of 768). 1 wave/row.
// ---------------------------------------------------------------------------
__global__ __launch_bounds__(256) void k3_stats(
    const u16* __restrict__ ykv16, float* __restrict__ mu, float* __restrict__ rs) {
  const int row = blockIdx.x * 4 + (threadIdx.x >> 6);
  const int lane = threadIdx.x & 63;
  const u16* p = ykv16 + (size_t)row * DD;
  float sum = 0.f, sq = 0.f;
#pragma unroll
  for (int i = 0; i < 3; ++i) {
    ushort4 v = *(const ushort4*)&p[(lane << 2) + i * 256];
    float f0 = b2f(v.x), f1 = b2f(v.y), f2 = b2f(v.z), f3 = b2f(v.w);
    sum += f0 + f1 + f2 + f3;
    sq += f0 * f0 + f1 * f1 + f2 * f2 + f3 * f3;
  }
#pragma unroll
  for (int off = 32; off; off >>= 1) {
    sum += __shfl_xor(sum, off);
    sq += __shfl_xor(sq, off);
  }
  if (lane == 0) {
    float m = sum * (1.f / 768.f);
    float v = sq * (1.f / 768.f) - m * m;
    mu[row] = m;
    rs[row] = rsqrtf(v + 1e-5f);
  }
}

// ---------------------------------------------------------------------------
// K4: raw GEMM ykv16 @ ENCVT[h]^T with LN as epilogue affine; xs via inverse
// rope of QR16 (CS table); out2 = xs*ys (fp32); XY (bf16) written IN PLACE
// into QR16's storage.  BK=64 pipeline, single-pass full-tile epilogue.
// ---------------------------------------------------------------------------
__global__ __launch_bounds__(256) void k4_xy(
    const u16* __restrict__ ykv16, const u16* __restrict__ encvt,
    const float2* __restrict__ CS,
    u16* __restrict__ qrxy, const float* __restrict__ mu,
    const float* __restrict__ rs, const float* __restrict__ colsum,
    float* __restrict__ out2, int bh0) {
  const int z = blockIdx.z;
  const int bh = bh0 + z, h = bh % NHH;
  const int t0 = blockIdx.x * 128, n0 = blockIdx.y * 128;
  GEMM_PROLOGUE();
  PIPELINED_K_LOOP64(ykv16 + ((size_t)z * TT + t0) * DD, DD,
                     encvt + ((size_t)h * NN + n0) * DD, DD, DD);
  __syncthreads();
#pragma unroll
  for (int i = 0; i < 4; ++i) {
    float muv[4], rsv[4];
#pragma unroll
    for (int r = 0; r < 4; ++r) {
      const int lrow = z * TT + t0 + wr * 64 + i * 16 + quad * 4 + r;
      muv[r] = mu[lrow];
      rsv[r] = rs[lrow];
    }
#pragma unroll
    for (int j = 0; j < 4; ++j) {
      const int n = n0 + wc * 64 + j * 16 + col16;
      const float csum = colsum[h * NN + n];
#pragma unroll
      for (int r = 0; r < 4; ++r) {
        const int lrow = wr * 64 + i * 16 + quad * 4 + r;
        const int t = t0 + lrow;
        const float ys = fmaxf(rsv[r] * acc[i][j][r] - rsv[r] * muv[r] * csum, 0.f);
        const size_t gi = ((size_t)bh * TT + t) * NN + n;
        const unsigned pq = *(const unsigned*)&qrxy[gi & ~(size_t)1];
        const float lo = b2f((u16)pq), hi = b2f((u16)(pq >> 16));
        const float2 cs = CS[t * 128 + (n >> 1)];
        const float xs = (n & 1) ? (hi * cs.x - lo * cs.y)
                                 : (lo * cs.x + hi * cs.y);
        const float val = ys * xs;
        out2[gi] = val;
        smem[lrow * 128 + wc * 64 + j * 16 + col16] = f2b(val);
      }
    }
  }
  __syncthreads();
  copy_out128(smem, qrxy + ((size_t)bh * TT + t0) * NN + n0, NN, tid);
}

// ---------------------------------------------------------------------------
// K5: ymlp = flat(XY) @ DECT^T.  M=4096, N=768, K=3072.  64x64 tiles,
// BK=64, TRIPLE-buffered (2-deep prefetch, vmcnt(8)) to hide the xyq
// gather latency; 4 async16/thread/phase.
// ---------------------------------------------------------------------------
__global__ __launch_bounds__(256) void k5_mlp(
    const u16* __restrict__ xyq, const u16* __restrict__ dect,
    float* __restrict__ ymlp) {
  __shared__ __attribute__((aligned(16))) u16 sm[24576];
  const int tid = threadIdx.x;
  const int w = tid >> 6, lane = tid & 63;
  const int wr = w >> 1, wc = w & 1;
  const int m16 = lane & 15, quad = lane >> 4;
  const int m0 = blockIdx.x * 64, d0 = blockIdx.y * 64;
  f32x4 acc[2][2];
#pragma unroll
  for (int i = 0; i < 2; ++i)
#pragma unroll
    for (int j = 0; j < 2; ++j) acc[i][j] = (f32x4){0.f, 0.f, 0.f, 0.f};
  const int ar = w * 16 + (lane >> 2);      // A row within 64-tile
  const int m = m0 + ar;
  const int b = m >> 11, t = m & (TT - 1);
  const int kc = (lane & 3) << 3;
#define K5_STAGE(buf, k0)                                                   \
  {                                                                         \
    const int hh_ = (k0) >> 8;                                              \
    const int kk_ = ((k0) & 255) + kc;                                      \
    const u16* ap_ = xyq + ((size_t)(b * NHH + hh_) * TT + t) * NN;         \
    async16(ap_ + kk_, (buf) + w * 512);                                    \
    async16(ap_ + kk_ + 32, (buf) + 2048 + w * 512);                        \
    stage64x32(dect + (size_t)d0 * (NHH * NN) + (k0), NHH * NN,             \
               (buf) + 4096, tid);                                          \
    stage64x32(dect + (size_t)d0 * (NHH * NN) + (k0) + 32, NHH * NN,        \
               (buf) + 6144, tid);                                          \
  }
  const int NK = (NHH * NN) / 64;           // 48 phases
  u16 *b0 = sm, *b1 = sm + 8192, *b2 = sm + 16384;
  K5_STAGE(b0, 0);
  K5_STAGE(b1, 64);
  for (int s = 0; s < NK; ++s) {
    if (s + 2 < NK) {
      K5_STAGE(b2, (s + 2) * 64);
      asm volatile("s_waitcnt vmcnt(8)" ::: "memory");
    } else if (s + 1 < NK) {
      asm volatile("s_waitcnt vmcnt(4)" ::: "memory");
    } else {
      asm volatile("s_waitcnt vmcnt(0)" ::: "memory");
    }
    __builtin_amdgcn_s_barrier();
    __builtin_amdgcn_sched_barrier(0);
#pragma unroll
    for (int half = 0; half < 2; ++half) {
      bf16x8 a[2], bb[2];
#pragma unroll
      for (int i = 0; i < 2; ++i)
        a[i] = *(const bf16x8*)&b0[half * 2048 + (wr * 32 + i * 16 + m16) * 32 + quad * 8];
#pragma unroll
      for (int j = 0; j < 2; ++j)
        bb[j] = *(const bf16x8*)&b0[4096 + half * 2048 + (wc * 32 + j * 16 + m16) * 32 + quad * 8];
#pragma unroll
      for (int i = 0; i < 2; ++i)
#pragma unroll
        for (int j = 0; j < 2; ++j)
          acc[i][j] = __builtin_amdgcn_mfma_f32_16x16x32_bf16(a[i], bb[j], acc[i][j], 0, 0, 0);
    }
    __builtin_amdgcn_sched_barrier(0);
    __builtin_amdgcn_s_barrier();
    u16* tmp = b0; b0 = b1; b1 = b2; b2 = tmp;
  }
#undef K5_STAGE
#pragma unroll
  for (int i = 0; i < 2; ++i)
#pragma unroll
    for (int j = 0; j < 2; ++j) {
      const int d = d0 + wc * 32 + j * 16 + m16;
#pragma unroll
      for (int r = 0; r < 4; ++r) {
        const int mm = m0 + wr * 32 + i * 16 + quad * 4 + r;
        ymlp[(size_t)mm * DD + d] = acc[i][j][r];
      }
    }
}

// ---------------------------------------------------------------------------
// K6: y = ln(ymlp)*sqrt(0.1/(ra+1e-6))*scale; out1 = ln(x+y). Block per row.
// ---------------------------------------------------------------------------
__global__ __launch_bounds__(256) void k6_final(
    const float* __restrict__ ymlp, const float* __restrict__ x,
    const float* __restrict__ scale, const float* __restrict__ ra,
    float* __restrict__ out1) {
  const int row = blockIdx.x;
  const int tid = threadIdx.x;
  const int wid = tid >> 6, lane = tid & 63;
  __shared__ float red[8];
  float v[3];
  float sum = 0.f, sq = 0.f;
#pragma unroll
  for (int j = 0; j < 3; ++j) {
    v[j] = ymlp[(size_t)row * DD + tid + j * 256];
    sum += v[j]; sq += v[j] * v[j];
  }
#pragma unroll
  for (int off = 32; off; off >>= 1) { sum += __shfl_xor(sum, off); sq += __shfl_xor(sq, off); }
  if (lane == 0) { red[wid] = sum; red[4 + wid] = sq; }
  __syncthreads();
  sum = red[0] + red[1] + red[2] + red[3];
  sq = red[4] + red[5] + red[6] + red[7];
  const float m1 = sum * (1.f / 768.f);
  const float r1 = rsqrtf(sq * (1.f / 768.f) - m1 * m1 + 1e-5f);
  float z[3];
  float sum2 = 0.f, sq2 = 0.f;
#pragma unroll
  for (int j = 0; j < 3; ++j) {
    const int d = tid + j * 256;
    float y = (v[j] - m1) * r1 * sqrtf(0.1f / (ra[d] + 1e-6f)) * scale[d];
    z[j] = x[(size_t)row * DD + d] + y;
    sum2 += z[j]; sq2 += z[j] * z[j];
  }
  __syncthreads();
#pragma unroll
  for (int off = 32; off; off >>= 1) { sum2 += __shfl_xor(sum2, off); sq2 += __shfl_xor(sq2, off); }
  if (lane == 0) { red[wid] = sum2; red[4 + wid] = sq2; }
  __syncthreads();
  sum2 = red[0] + red[1] + red[2] + red[3];
  sq2 = red[4] + red[5] + red[6] + red[7];
  const float m2 = sum2 * (1.f / 768.f);
  const float r2 = rsqrtf(sq2 * (1.f / 768.f) - m2 * m2 + 1e-5f);
#pragma unroll
  for (int j = 0; j < 3; ++j)
    out1[(size_t)row * DD + tid + j * 256] = (z[j] - m2) * r2;
}

// ---------------------------------------------------------------------------
extern "C" void kernel_launch(void* const* d_in, const int* in_sizes, int n_in,
                              void* d_out, int out_size, void* d_ws, size_t ws_size,
                              hipStream_t stream) {
  const float* x = (const float*)d_in[0];
  const float* enc = (const float*)d_in[1];
  const float* encv = (const float*)d_in[2];
  const float* dec = (const float*)d_in[3];
  const float* scale = (const float*)d_in[4];
  const float* ra = (const float*)d_in[5];
  float* out1 = (float*)d_out;
  float* out2 = out1 + (size_t)BB * TT * DD;
  float* ymlp = out1;                         // k5 scratch, k6 in-place

  const int NS = BB * NHH;  // 24 slices
  unsigned char* p = (unsigned char*)d_ws;
  u16* X16 = (u16*)p;    p += (size_t)BB * TT * DD * 2;
  u16* XT16 = (u16*)p;   p += (size_t)BB * DD * TT * 2;
  u16* ENCT = (u16*)p;   p += (size_t)NHH * NN * DD * 2;
  u16* ENCVT = (u16*)p;  p += (size_t)NHH * NN * DD * 2;
  u16* DECT = (u16*)p;   p += (size_t)DD * NHH * NN * 2;
  u16* QR16 = (u16*)p;   p += (size_t)NS * TT * NN * 2;   // holds QR, then XY
  u16* QRT16 = (u16*)p;  p += (size_t)NS * NN * TT * 2;
  float* COLSUM = (float*)p; p += (size_t)NHH * NN * 4;
  float2* CS = (float2*)p;   p += (size_t)TT * (NN / 2) * sizeof(float2);
  const size_t SLICE_B = (size_t)TT * CH * 2 + 3 * (size_t)DD * NN * 2 +
                         (size_t)TT * DD * 2 + (size_t)TT * 8;
  size_t fixed = (size_t)(p - (unsigned char*)d_ws);
  size_t rem = (ws_size > fixed) ? ws_size - fixed : 0;
  int GSmax = (int)(rem / SLICE_B);
  if (GSmax < 1) GSmax = 1;
  if (GSmax > NS) GSmax = NS;
  const int ngrp = (NS + GSmax - 1) / GSmax;
  const int GS = (NS + ngrp - 1) / ngrp;     // balanced groups
  u16* SB = (u16*)p;     p += (size_t)GS * TT * CH * 2;
  u16* H16 = (u16*)p;    p += (size_t)GS * 3 * DD * NN * 2;
  u16* YKV16 = (u16*)p;  p += (size_t)GS * TT * DD * 2;
  float* MU = (float*)p; p += (size_t)GS * TT * 4;
  float* RS = (float*)p; p += (size_t)GS * TT * 4;

  // One-time conversions / transposes
  cvt_bf16<<<dim3((BB * TT * DD) / 1024), 256, 0, stream>>>(x, X16, (size_t)BB * TT * DD / 4);
  tcvt_bf16<<<dim3(DD / 32, TT / 32, BB), 256, 0, stream>>>(
      x, XT16, TT, DD, (size_t)TT * DD, (size_t)DD * TT);
  tcvt_bf16<<<dim3(NN / 32, DD / 32, NHH), 256, 0, stream>>>(
      enc, ENCT, DD, NN, (size_t)DD * NN, (size_t)NN * DD);
  tcvt_bf16<<<dim3(NN / 32, DD / 32, NHH), 256, 0, stream>>>(
      encv, ENCVT, DD, NN, (size_t)DD * NN, (size_t)NN * DD);
  tcvt_bf16<<<dim3(DD / 32, (NHH * NN) / 32, 1), 256, 0, stream>>>(
      dec, DECT, NHH * NN, DD, 0, 0);
  k_colsum<<<dim3(NHH * NN / 4), 256, 0, stream>>>(ENCVT, COLSUM);
  k_cstab<<<dim3(TT * (NN / 2) / 256), 256, 0, stream>>>(CS);

  k1_encode<<<dim3(BB * TT / 128, NN / 128, NHH), 256, 0, stream>>>(
      X16, ENCT, CS, QR16, QRT16);

  for (int bh0 = 0; bh0 < NS; bh0 += GS) {
    const int gs = imin(GS, NS - bh0);
    kS_band<<<dim3(40, gs), 256, 0, stream>>>(QR16, SB, bh0);
    kB_all<<<dim3(DD / 64, NN / 128, gs), 256, 0, stream>>>(
        XT16, QRT16, H16, bh0);
    kA_attn<<<dim3(96 * gs), 256, 0, stream>>>(
        QR16, H16, SB, XT16, YKV16, bh0);
    k3_stats<<<dim3(gs * TT / 4), 256, 0, stream>>>(YKV16, MU, RS);
    k4_xy<<<dim3(TT / 128, NN / 128, gs), 256, 0, stream>>>(
        YKV16, ENCVT, CS, QR16, MU, RS, COLSUM, out2, bh0);
  }

  k5_mlp<<<dim3(BB * TT / 64, DD / 64), 256, 0, stream>>>(QR16, DECT, ymlp);
  k6_final<<<dim3(BB * TT), 256, 0, stream>>>(ymlp, x, scale, ra, out1);
}